// Round 14
// baseline (651.232 us; speedup 1.0000x reference)
//
#include <hip/hip_runtime.h>
#include <cstdint>
#include <cstddef>

#define T_TOK 4096
#define H_DIM 1024
#define I_DIM 2816
#define E_NUM 9
#define MAXTILE 76

typedef __bf16 bf16;
typedef bf16 bf16x4 __attribute__((ext_vector_type(4)));
typedef bf16 bf16x8 __attribute__((ext_vector_type(8)));
typedef float f32x4 __attribute__((ext_vector_type(4)));

constexpr int BM = 128, BN = 128, BK = 32;
constexpr int HTILE = BM * BK;          // 4096 elems = 8KB per half

// async global->LDS, 16B per lane; LDS dest must be linear (wave-uniform base + lane*16)
#define GL16(gp, lp)                                                                   \
  __builtin_amdgcn_global_load_lds((const __attribute__((address_space(1))) void*)(gp), \
                                   (__attribute__((address_space(3))) void*)(lp), 16, 0, 0)

// ---------------- x: fp32 -> bf16 ----------------
__global__ __launch_bounds__(256) void k_xcast(const float* __restrict__ x, bf16* __restrict__ xb) {
  size_t i = ((size_t)blockIdx.x * 256 + threadIdx.x) * 8;
  float4 a = *reinterpret_cast<const float4*>(x + i);
  float4 b = *reinterpret_cast<const float4*>(x + i + 4);
  bf16x8 v;
  v[0]=(bf16)a.x; v[1]=(bf16)a.y; v[2]=(bf16)a.z; v[3]=(bf16)a.w;
  v[4]=(bf16)b.x; v[5]=(bf16)b.y; v[6]=(bf16)b.z; v[7]=(bf16)b.w;
  *reinterpret_cast<bf16x8*>(xb + i) = v;
}

// ------- transpose+convert core: one 64x64 tile, vectorized 16B writes -------
__device__ __forceinline__ void transpose_tile(const float* __restrict__ src,
                                               bf16* __restrict__ dst, int R, int C) {
  __shared__ bf16 tile[64][68];
  int r0 = blockIdx.y * 64, c0 = blockIdx.x * 64;
  int t = threadIdx.x;
  int tr = t >> 4, tc = (t & 15) * 4;
#pragma unroll
  for (int it = 0; it < 4; ++it) {
    int r = tr + it * 16;
    float4 v = *reinterpret_cast<const float4*>(src + (size_t)(r0 + r) * C + c0 + tc);
    bf16x4 w; w[0]=(bf16)v.x; w[1]=(bf16)v.y; w[2]=(bf16)v.z; w[3]=(bf16)v.w;
    *reinterpret_cast<bf16x4*>(&tile[r][tc]) = w;
  }
  __syncthreads();
  int oc = t >> 2;
  int q  = t & 3;
  bf16x8 w0, w1;
#pragma unroll
  for (int j = 0; j < 8; ++j) w0[j] = tile[q * 16 + j][oc];
#pragma unroll
  for (int j = 0; j < 8; ++j) w1[j] = tile[q * 16 + 8 + j][oc];
  bf16* dp = dst + (size_t)(c0 + oc) * R + r0 + q * 16;
  *reinterpret_cast<bf16x8*>(dp)     = w0;
  *reinterpret_cast<bf16x8*>(dp + 8) = w1;
}

// fused Wg+Wu transpose: z in [0,18): z<9 -> Wg, else Wu. [H][I] -> [I][H]
__global__ __launch_bounds__(256) void k_transpose_gu(const float* __restrict__ Wg,
                                                      const float* __restrict__ Wu,
                                                      bf16* __restrict__ WgT,
                                                      bf16* __restrict__ WuT) {
  int z = blockIdx.z;
  const float* src = (z < 9) ? (Wg + (size_t)z * H_DIM * I_DIM)
                             : (Wu + (size_t)(z - 9) * H_DIM * I_DIM);
  bf16* dst = (z < 9) ? (WgT + (size_t)z * H_DIM * I_DIM)
                      : (WuT + (size_t)(z - 9) * H_DIM * I_DIM);
  transpose_tile(src, dst, H_DIM, I_DIM);
}

// Wd transpose: [I][H] -> [H][I]
__global__ __launch_bounds__(256) void k_transpose_d(const float* __restrict__ Wd,
                                                     bf16* __restrict__ WdT) {
  const float* src = Wd + (size_t)blockIdx.z * I_DIM * H_DIM;
  bf16* dst = WdT + (size_t)blockIdx.z * I_DIM * H_DIM;
  transpose_tile(src, dst, I_DIM, H_DIM);
}

// ---------------- router: fp32 logits, softmax top-2, renormalized ----------------
__global__ __launch_bounds__(256) void k_router(const float* __restrict__ x,
                                                const float* __restrict__ Wr,
                                                int* __restrict__ ridx,
                                                float* __restrict__ rw,
                                                int* __restrict__ counts) {
  int lane = threadIdx.x & 63;
  int wid  = threadIdx.x >> 6;
  int t = blockIdx.x * 4 + wid;
  const float* xr = x + (size_t)t * H_DIM;
  float acc[E_NUM];
#pragma unroll
  for (int e = 0; e < E_NUM; ++e) acc[e] = 0.f;
  for (int h = lane; h < H_DIM; h += 64) {
    float xv = xr[h];
    const float* wr = Wr + h * E_NUM;
#pragma unroll
    for (int e = 0; e < E_NUM; ++e) acc[e] += xv * wr[e];
  }
#pragma unroll
  for (int off = 32; off > 0; off >>= 1) {
#pragma unroll
    for (int e = 0; e < E_NUM; ++e) acc[e] += __shfl_xor(acc[e], off);
  }
  if (lane == 0) {
    int i0 = 0;
#pragma unroll
    for (int e = 1; e < E_NUM; ++e) if (acc[e] > acc[i0]) i0 = e;
    int i1 = (i0 == 0) ? 1 : 0;
#pragma unroll
    for (int e = 0; e < E_NUM; ++e) if (e != i0 && acc[e] > acc[i1]) i1 = e;
    float r  = expf(acc[i1] - acc[i0]);
    float w0 = 1.f / (1.f + r);
    float w1 = r / (1.f + r);
    ridx[2 * t]     = i0;
    ridx[2 * t + 1] = i1;
    rw[2 * t]     = w0;
    rw[2 * t + 1] = w1;
    atomicAdd(&counts[i0], 1);
    atomicAdd(&counts[i1], 1);
  }
}

// ------- scan: counts -> offsets, compact tile list, zero cursors -------
__global__ void k_scan(const int* __restrict__ counts, int* __restrict__ offsets,
                       int* __restrict__ cursor, int* __restrict__ tiles,
                       int* __restrict__ n_tiles) {
  if (threadIdx.x == 0) {
    int s = 0, nt = 0;
    for (int e = 0; e < E_NUM; ++e) {
      offsets[e] = s;
      int c = counts[e];
      for (int pt = 0; pt * BM < c && nt < MAXTILE; ++pt) tiles[nt++] = (e << 16) | pt;
      s += c;
    }
    offsets[E_NUM] = s;
    *n_tiles = nt;
  }
  if (threadIdx.x < E_NUM) cursor[threadIdx.x] = 0;
}

// ---------------- scatter pair ids into expert-sorted perm ----------------
__global__ __launch_bounds__(256) void k_scatter(const int* __restrict__ ridx,
                                                 const int* __restrict__ offsets,
                                                 int* __restrict__ cursor,
                                                 int* __restrict__ perm) {
  int t = blockIdx.x * 256 + threadIdx.x;
  if (t >= T_TOK) return;
#pragma unroll
  for (int k = 0; k < 2; ++k) {
    int e = ridx[2 * t + k];
    int pos = atomicAdd(&cursor[e], 1);
    perm[offsets[e] + pos] = 2 * t + k;
  }
}

// ------- fused gate+up grouped GEMM: BK=64/barrier-pair, 3 blocks/CU -------
// (256,3): VGPR cap ~168 >= measured 104 (no spill; (256,4)'s cap 128 spilled in R8).
// LDS 48KB x 3 = 144 <= 160KB. 3rd resident block hides the per-iteration vmcnt drain.
__global__ __launch_bounds__(256, 3) void k_gateup(const bf16* __restrict__ xb,
                                                   const bf16* __restrict__ WgT,
                                                   const bf16* __restrict__ WuT,
                                                   const int* __restrict__ perm,
                                                   const int* __restrict__ offsets,
                                                   const int* __restrict__ tiles,
                                                   const int* __restrict__ n_tiles,
                                                   bf16* __restrict__ hidden) {
  if ((int)blockIdx.y >= *n_tiles) return;
  int tv = tiles[blockIdx.y];
  int e = tv >> 16, pt = tv & 0xffff;
  int seg0 = offsets[e], cnt = offsets[e + 1] - seg0;
  int n0 = blockIdx.x * BN;

  __shared__ bf16 As[2 * HTILE];   // halves at 0, HTILE
  __shared__ bf16 Bg[2 * HTILE];
  __shared__ bf16 Bu[2 * HTILE];

  int tid = threadIdx.x, lane = tid & 63, wid = tid >> 6;
  int wm = wid >> 1, wn = wid & 1, l15 = lane & 15, l16 = lane >> 4;

  int srow1 = tid >> 2, srow2 = 64 + srow1;
  int kc = (tid & 3) * 8;
  int p1 = pt * BM + srow1, p2 = pt * BM + srow2;
  const bf16* a1 = xb + (size_t)(perm[seg0 + (p1 < cnt ? p1 : 0)] >> 1) * H_DIM + kc;
  const bf16* a2 = xb + (size_t)(perm[seg0 + (p2 < cnt ? p2 : 0)] >> 1) * H_DIM + kc;
  const bf16* g1 = WgT + ((size_t)e * I_DIM + n0 + srow1) * H_DIM + kc;
  const bf16* g2 = WgT + ((size_t)e * I_DIM + n0 + srow2) * H_DIM + kc;
  const bf16* u1 = WuT + ((size_t)e * I_DIM + n0 + srow1) * H_DIM + kc;
  const bf16* u2 = WuT + ((size_t)e * I_DIM + n0 + srow2) * H_DIM + kc;
  bf16* lA1 = &As[tid * 8];       bf16* lA2 = &As[2048 + tid * 8];
  bf16* lG1 = &Bg[tid * 8];       bf16* lG2 = &Bg[2048 + tid * 8];
  bf16* lU1 = &Bu[tid * 8];       bf16* lU2 = &Bu[2048 + tid * 8];

  f32x4 accg[4][4], accu[4][4];
#pragma unroll
  for (int m = 0; m < 4; ++m)
#pragma unroll
    for (int n = 0; n < 4; ++n) {
      accg[m][n] = (f32x4){0.f, 0.f, 0.f, 0.f};
      accu[m][n] = (f32x4){0.f, 0.f, 0.f, 0.f};
    }

  for (int k0 = 0; k0 < H_DIM; k0 += 2 * BK) {
    GL16(a1 + k0, lA1);            GL16(a2 + k0, lA2);
    GL16(a1 + k0 + BK, lA1 + HTILE); GL16(a2 + k0 + BK, lA2 + HTILE);
    GL16(g1 + k0, lG1);            GL16(g2 + k0, lG2);
    GL16(g1 + k0 + BK, lG1 + HTILE); GL16(g2 + k0 + BK, lG2 + HTILE);
    GL16(u1 + k0, lU1);            GL16(u2 + k0, lU2);
    GL16(u1 + k0 + BK, lU1 + HTILE); GL16(u2 + k0 + BK, lU2 + HTILE);
    __syncthreads();               // drains vmcnt -> both halves ready

#pragma unroll
    for (int kk = 0; kk < 2; ++kk) {
      const bf16* Ab = &As[kk * HTILE];
      const bf16* Gb = &Bg[kk * HTILE];
      const bf16* Ub = &Bu[kk * HTILE];
      bf16x8 af[4], bg[4], bu[4];
#pragma unroll
      for (int m = 0; m < 4; ++m)
        af[m] = *reinterpret_cast<const bf16x8*>(&Ab[(wm * 64 + m * 16 + l15) * BK + l16 * 8]);
#pragma unroll
      for (int n = 0; n < 4; ++n) {
        bg[n] = *reinterpret_cast<const bf16x8*>(&Gb[(wn * 64 + n * 16 + l15) * BK + l16 * 8]);
        bu[n] = *reinterpret_cast<const bf16x8*>(&Ub[(wn * 64 + n * 16 + l15) * BK + l16 * 8]);
      }
#pragma unroll
      for (int m = 0; m < 4; ++m)
#pragma unroll
        for (int n = 0; n < 4; ++n) {
          accg[m][n] = __builtin_amdgcn_mfma_f32_16x16x32_bf16(af[m], bg[n], accg[m][n], 0, 0, 0);
          accu[m][n] = __builtin_amdgcn_mfma_f32_16x16x32_bf16(af[m], bu[n], accu[m][n], 0, 0, 0);
        }
    }
    __syncthreads();
  }

#pragma unroll
  for (int m = 0; m < 4; ++m) {
#pragma unroll
    for (int r = 0; r < 4; ++r) {
      int p_glob = pt * BM + wm * 64 + m * 16 + l16 * 4 + r;
      if (p_glob < cnt) {
        bf16* hrow = hidden + (size_t)(seg0 + p_glob) * I_DIM;
#pragma unroll
        for (int n = 0; n < 4; ++n) {
          int col = n0 + wn * 64 + n * 16 + l15;
          float g = accg[m][n][r];
          float u = accu[m][n][r];
          float h = g / (1.f + __expf(-g)) * u;
          hrow[col] = (bf16)h;
        }
      }
    }
  }
}

// ------- down grouped GEMM: split-K x2 bf16 partials, 3 blocks/CU -------
__global__ __launch_bounds__(256, 3) void k_down(const bf16* __restrict__ hidden,
                                                 const bf16* __restrict__ WdT,
                                                 const int* __restrict__ perm,
                                                 const int* __restrict__ offsets,
                                                 const int* __restrict__ tiles,
                                                 const int* __restrict__ n_tiles,
                                                 bf16* __restrict__ pair_half) {
  if ((int)blockIdx.y >= *n_tiles) return;
  int tv = tiles[blockIdx.y];
  int e = tv >> 16, pt = tv & 0xffff;
  int seg0 = offsets[e], cnt = offsets[e + 1] - seg0;
  int n0 = blockIdx.x * BN;
  int kz = blockIdx.z * (I_DIM / 2);
  bf16* pout = pair_half + (size_t)blockIdx.z * 2 * T_TOK * H_DIM;

  __shared__ bf16 As[2 * HTILE];
  __shared__ bf16 Bs[2 * HTILE];

  int tid = threadIdx.x, lane = tid & 63, wid = tid >> 6;
  int wm = wid >> 1, wn = wid & 1, l15 = lane & 15, l16 = lane >> 4;

  int srow1 = tid >> 2, srow2 = 64 + srow1;
  int kc = (tid & 3) * 8;
  int p1 = pt * BM + srow1, p2 = pt * BM + srow2;
  const bf16* a1 = hidden + (size_t)(seg0 + (p1 < cnt ? p1 : 0)) * I_DIM + kz + kc;
  const bf16* a2 = hidden + (size_t)(seg0 + (p2 < cnt ? p2 : 0)) * I_DIM + kz + kc;
  const bf16* b1 = WdT + ((size_t)e * H_DIM + n0 + srow1) * I_DIM + kz + kc;
  const bf16* b2 = WdT + ((size_t)e * H_DIM + n0 + srow2) * I_DIM + kz + kc;
  bf16* lA1 = &As[tid * 8];  bf16* lA2 = &As[2048 + tid * 8];
  bf16* lB1 = &Bs[tid * 8];  bf16* lB2 = &Bs[2048 + tid * 8];

  f32x4 acc[4][4];
#pragma unroll
  for (int m = 0; m < 4; ++m)
#pragma unroll
    for (int n = 0; n < 4; ++n) acc[m][n] = (f32x4){0.f, 0.f, 0.f, 0.f};

  for (int k0 = 0; k0 < I_DIM / 2; k0 += 2 * BK) {
    GL16(a1 + k0, lA1);            GL16(a2 + k0, lA2);
    GL16(a1 + k0 + BK, lA1 + HTILE); GL16(a2 + k0 + BK, lA2 + HTILE);
    GL16(b1 + k0, lB1);            GL16(b2 + k0, lB2);
    GL16(b1 + k0 + BK, lB1 + HTILE); GL16(b2 + k0 + BK, lB2 + HTILE);
    __syncthreads();

#pragma unroll
    for (int kk = 0; kk < 2; ++kk) {
      const bf16* Ab = &As[kk * HTILE];
      const bf16* Bb = &Bs[kk * HTILE];
      bf16x8 af[4], bfr[4];
#pragma unroll
      for (int m = 0; m < 4; ++m)
        af[m] = *reinterpret_cast<const bf16x8*>(&Ab[(wm * 64 + m * 16 + l15) * BK + l16 * 8]);
#pragma unroll
      for (int n = 0; n < 4; ++n)
        bfr[n] = *reinterpret_cast<const bf16x8*>(&Bb[(wn * 64 + n * 16 + l15) * BK + l16 * 8]);
#pragma unroll
      for (int m = 0; m < 4; ++m)
#pragma unroll
        for (int n = 0; n < 4; ++n)
          acc[m][n] = __builtin_amdgcn_mfma_f32_16x16x32_bf16(af[m], bfr[n], acc[m][n], 0, 0, 0);
    }
    __syncthreads();
  }

#pragma unroll
  for (int m = 0; m < 4; ++m) {
#pragma unroll
    for (int r = 0; r < 4; ++r) {
      int p_glob = pt * BM + wm * 64 + m * 16 + l16 * 4 + r;
      if (p_glob < cnt) {
        int pair = perm[seg0 + p_glob];
        bf16* orow = pout + (size_t)pair * H_DIM;
#pragma unroll
        for (int n = 0; n < 4; ++n) {
          int col = n0 + wn * 64 + n * 16 + l15;
          orow[col] = (bf16)acc[m][n][r];
        }
      }
    }
  }
}

// ------- combine: out[t] = w0*(z0[2t]+z1[2t]) + w1*(z0[2t+1]+z1[2t+1]) -------
__global__ __launch_bounds__(256) void k_combine(const bf16* __restrict__ pair_half,
                                                 const float* __restrict__ rw,
                                                 float* __restrict__ out) {
  int t = blockIdx.x;
  int c = threadIdx.x;
  const bf16* z0 = pair_half;
  const bf16* z1 = pair_half + (size_t)2 * T_TOK * H_DIM;
  float w0 = rw[2 * t];
  float w1 = rw[2 * t + 1];
  size_t r0 = (size_t)(2 * t) * H_DIM + c * 4;
  size_t r1 = (size_t)(2 * t + 1) * H_DIM + c * 4;
  bf16x4 a0 = *reinterpret_cast<const bf16x4*>(z0 + r0);
  bf16x4 a1 = *reinterpret_cast<const bf16x4*>(z1 + r0);
  bf16x4 b0 = *reinterpret_cast<const bf16x4*>(z0 + r1);
  bf16x4 b1 = *reinterpret_cast<const bf16x4*>(z1 + r1);
  float4 o;
  o.x = w0 * ((float)a0[0] + (float)a1[0]) + w1 * ((float)b0[0] + (float)b1[0]);
  o.y = w0 * ((float)a0[1] + (float)a1[1]) + w1 * ((float)b0[1] + (float)b1[1]);
  o.z = w0 * ((float)a0[2] + (float)a1[2]) + w1 * ((float)b0[2] + (float)b1[2]);
  o.w = w0 * ((float)a0[3] + (float)a1[3]) + w1 * ((float)b0[3] + (float)b1[3]);
  *reinterpret_cast<float4*>(out + (size_t)t * H_DIM + c * 4) = o;
}

extern "C" void kernel_launch(void* const* d_in, const int* in_sizes, int n_in,
                              void* d_out, int out_size, void* d_ws, size_t ws_size,
                              hipStream_t stream) {
  const float* x  = (const float*)d_in[0];
  const float* Wr = (const float*)d_in[1];
  const float* Wg = (const float*)d_in[2];
  const float* Wu = (const float*)d_in[3];
  const float* Wd = (const float*)d_in[4];
  float* out = (float*)d_out;

  char* ws = (char*)d_ws;
  int*   counts  = (int*)(ws);
  int*   cursor  = (int*)(ws + 256);
  int*   offsets = (int*)(ws + 512);
  int*   n_tiles = (int*)(ws + 768);
  int*   tiles   = (int*)(ws + 1024);
  int*   ridx    = (int*)(ws + 64 * 1024);
  float* rw      = (float*)(ws + 128 * 1024);
  int*   perm    = (int*)(ws + 192 * 1024);
  bf16*  xb      = (bf16*)(ws + (1ull << 20));
  bf16*  WgT     = (bf16*)(ws + (16ull << 20));
  bf16*  WuT     = (bf16*)(ws + (66ull << 20));
  bf16*  WdT     = (bf16*)(ws + (116ull << 20));
  bf16*  hidden  = (bf16*)(ws + (166ull << 20));
  bf16*  pair_half = (bf16*)(ws + (212ull << 20));   // [2][8192][1024] bf16 = 32 MiB

  hipMemsetAsync(counts, 0, 64, stream);
  k_xcast<<<dim3(T_TOK * H_DIM / 2048), dim3(256), 0, stream>>>(x, xb);
  k_transpose_gu<<<dim3(I_DIM / 64, H_DIM / 64, 2 * E_NUM), dim3(256), 0, stream>>>(
      Wg, Wu, WgT, WuT);
  k_transpose_d<<<dim3(H_DIM / 64, I_DIM / 64, E_NUM), dim3(256), 0, stream>>>(Wd, WdT);
  k_router<<<dim3(T_TOK / 4), dim3(256), 0, stream>>>(x, Wr, ridx, rw, counts);
  k_scan<<<dim3(1), dim3(64), 0, stream>>>(counts, offsets, cursor, tiles, n_tiles);
  k_scatter<<<dim3((T_TOK + 255) / 256), dim3(256), 0, stream>>>(ridx, offsets, cursor, perm);
  k_gateup<<<dim3(I_DIM / BN, MAXTILE), dim3(256), 0, stream>>>(
      xb, WgT, WuT, perm, offsets, tiles, n_tiles, hidden);
  k_down<<<dim3(H_DIM / BN, MAXTILE, 2), dim3(256), 0, stream>>>(
      hidden, WdT, perm, offsets, tiles, n_tiles, pair_half);
  k_combine<<<dim3(T_TOK), dim3(256), 0, stream>>>(pair_half, rw, out);
}

// Round 15
// 477.558 us; speedup vs baseline: 1.3637x; 1.3637x over previous
//
#include <hip/hip_runtime.h>
#include <cstdint>
#include <cstddef>

#define T_TOK 4096
#define H_DIM 1024
#define I_DIM 2816
#define E_NUM 9
#define MAXTILE 76

typedef __bf16 bf16;
typedef bf16 bf16x4 __attribute__((ext_vector_type(4)));
typedef bf16 bf16x8 __attribute__((ext_vector_type(8)));
typedef float f32x4 __attribute__((ext_vector_type(4)));

constexpr int BM = 128, BN = 128, BK = 32;
constexpr int HTILE = BM * BK;          // 4096 elems = 8KB per half

// async global->LDS, 16B per lane; LDS dest must be linear (wave-uniform base + lane*16)
#define GL16(gp, lp)                                                                   \
  __builtin_amdgcn_global_load_lds((const __attribute__((address_space(1))) void*)(gp), \
                                   (__attribute__((address_space(3))) void*)(lp), 16, 0, 0)

// ---------------- x: fp32 -> bf16 ----------------
__global__ __launch_bounds__(256) void k_xcast(const float* __restrict__ x, bf16* __restrict__ xb) {
  size_t i = ((size_t)blockIdx.x * 256 + threadIdx.x) * 8;
  float4 a = *reinterpret_cast<const float4*>(x + i);
  float4 b = *reinterpret_cast<const float4*>(x + i + 4);
  bf16x8 v;
  v[0]=(bf16)a.x; v[1]=(bf16)a.y; v[2]=(bf16)a.z; v[3]=(bf16)a.w;
  v[4]=(bf16)b.x; v[5]=(bf16)b.y; v[6]=(bf16)b.z; v[7]=(bf16)b.w;
  *reinterpret_cast<bf16x8*>(xb + i) = v;
}

// ------- transpose+convert core: one 64x64 tile, vectorized 16B writes -------
__device__ __forceinline__ void transpose_tile(const float* __restrict__ src,
                                               bf16* __restrict__ dst, int R, int C) {
  __shared__ bf16 tile[64][68];
  int r0 = blockIdx.y * 64, c0 = blockIdx.x * 64;
  int t = threadIdx.x;
  int tr = t >> 4, tc = (t & 15) * 4;
#pragma unroll
  for (int it = 0; it < 4; ++it) {
    int r = tr + it * 16;
    float4 v = *reinterpret_cast<const float4*>(src + (size_t)(r0 + r) * C + c0 + tc);
    bf16x4 w; w[0]=(bf16)v.x; w[1]=(bf16)v.y; w[2]=(bf16)v.z; w[3]=(bf16)v.w;
    *reinterpret_cast<bf16x4*>(&tile[r][tc]) = w;
  }
  __syncthreads();
  int oc = t >> 2;
  int q  = t & 3;
  bf16x8 w0, w1;
#pragma unroll
  for (int j = 0; j < 8; ++j) w0[j] = tile[q * 16 + j][oc];
#pragma unroll
  for (int j = 0; j < 8; ++j) w1[j] = tile[q * 16 + 8 + j][oc];
  bf16* dp = dst + (size_t)(c0 + oc) * R + r0 + q * 16;
  *reinterpret_cast<bf16x8*>(dp)     = w0;
  *reinterpret_cast<bf16x8*>(dp + 8) = w1;
}

// fused Wg+Wu transpose: z in [0,18): z<9 -> Wg, else Wu. [H][I] -> [I][H]
__global__ __launch_bounds__(256) void k_transpose_gu(const float* __restrict__ Wg,
                                                      const float* __restrict__ Wu,
                                                      bf16* __restrict__ WgT,
                                                      bf16* __restrict__ WuT) {
  int z = blockIdx.z;
  const float* src = (z < 9) ? (Wg + (size_t)z * H_DIM * I_DIM)
                             : (Wu + (size_t)(z - 9) * H_DIM * I_DIM);
  bf16* dst = (z < 9) ? (WgT + (size_t)z * H_DIM * I_DIM)
                      : (WuT + (size_t)(z - 9) * H_DIM * I_DIM);
  transpose_tile(src, dst, H_DIM, I_DIM);
}

// Wd transpose: [I][H] -> [H][I]
__global__ __launch_bounds__(256) void k_transpose_d(const float* __restrict__ Wd,
                                                     bf16* __restrict__ WdT) {
  const float* src = Wd + (size_t)blockIdx.z * I_DIM * H_DIM;
  bf16* dst = WdT + (size_t)blockIdx.z * I_DIM * H_DIM;
  transpose_tile(src, dst, I_DIM, H_DIM);
}

// ---------------- router: fp32 logits, softmax top-2, renormalized ----------------
__global__ __launch_bounds__(256) void k_router(const float* __restrict__ x,
                                                const float* __restrict__ Wr,
                                                int* __restrict__ ridx,
                                                float* __restrict__ rw,
                                                int* __restrict__ counts) {
  int lane = threadIdx.x & 63;
  int wid  = threadIdx.x >> 6;
  int t = blockIdx.x * 4 + wid;
  const float* xr = x + (size_t)t * H_DIM;
  float acc[E_NUM];
#pragma unroll
  for (int e = 0; e < E_NUM; ++e) acc[e] = 0.f;
  for (int h = lane; h < H_DIM; h += 64) {
    float xv = xr[h];
    const float* wr = Wr + h * E_NUM;
#pragma unroll
    for (int e = 0; e < E_NUM; ++e) acc[e] += xv * wr[e];
  }
#pragma unroll
  for (int off = 32; off > 0; off >>= 1) {
#pragma unroll
    for (int e = 0; e < E_NUM; ++e) acc[e] += __shfl_xor(acc[e], off);
  }
  if (lane == 0) {
    int i0 = 0;
#pragma unroll
    for (int e = 1; e < E_NUM; ++e) if (acc[e] > acc[i0]) i0 = e;
    int i1 = (i0 == 0) ? 1 : 0;
#pragma unroll
    for (int e = 0; e < E_NUM; ++e) if (e != i0 && acc[e] > acc[i1]) i1 = e;
    float r  = expf(acc[i1] - acc[i0]);
    float w0 = 1.f / (1.f + r);
    float w1 = r / (1.f + r);
    ridx[2 * t]     = i0;
    ridx[2 * t + 1] = i1;
    rw[2 * t]     = w0;
    rw[2 * t + 1] = w1;
    atomicAdd(&counts[i0], 1);
    atomicAdd(&counts[i1], 1);
  }
}

// ------- scan: counts -> offsets, compact tile list, zero cursors -------
__global__ void k_scan(const int* __restrict__ counts, int* __restrict__ offsets,
                       int* __restrict__ cursor, int* __restrict__ tiles,
                       int* __restrict__ n_tiles) {
  if (threadIdx.x == 0) {
    int s = 0, nt = 0;
    for (int e = 0; e < E_NUM; ++e) {
      offsets[e] = s;
      int c = counts[e];
      for (int pt = 0; pt * BM < c && nt < MAXTILE; ++pt) tiles[nt++] = (e << 16) | pt;
      s += c;
    }
    offsets[E_NUM] = s;
    *n_tiles = nt;
  }
  if (threadIdx.x < E_NUM) cursor[threadIdx.x] = 0;
}

// ---------------- scatter pair ids into expert-sorted perm ----------------
__global__ __launch_bounds__(256) void k_scatter(const int* __restrict__ ridx,
                                                 const int* __restrict__ offsets,
                                                 int* __restrict__ cursor,
                                                 int* __restrict__ perm) {
  int t = blockIdx.x * 256 + threadIdx.x;
  if (t >= T_TOK) return;
#pragma unroll
  for (int k = 0; k < 2; ++k) {
    int e = ridx[2 * t + k];
    int pos = atomicAdd(&cursor[e], 1);
    perm[offsets[e] + pos] = 2 * t + k;
  }
}

// ------- fused gate+up grouped GEMM: BK=64/barrier-pair, (256,2) proven (146us) -------
// NOTE: (256,2) is the occupancy cliff edge — (256,3) and (256,4) both spill the
// 128-reg accumulator to scratch (R8: 4.2GB, R14: 554MB writes). Do not raise.
__global__ __launch_bounds__(256, 2) void k_gateup(const bf16* __restrict__ xb,
                                                   const bf16* __restrict__ WgT,
                                                   const bf16* __restrict__ WuT,
                                                   const int* __restrict__ perm,
                                                   const int* __restrict__ offsets,
                                                   const int* __restrict__ tiles,
                                                   const int* __restrict__ n_tiles,
                                                   bf16* __restrict__ hidden) {
  if ((int)blockIdx.y >= *n_tiles) return;
  int tv = tiles[blockIdx.y];
  int e = tv >> 16, pt = tv & 0xffff;
  int seg0 = offsets[e], cnt = offsets[e + 1] - seg0;
  int n0 = blockIdx.x * BN;

  __shared__ bf16 As[2 * HTILE];   // halves at 0, HTILE
  __shared__ bf16 Bg[2 * HTILE];
  __shared__ bf16 Bu[2 * HTILE];

  int tid = threadIdx.x, lane = tid & 63, wid = tid >> 6;
  int wm = wid >> 1, wn = wid & 1, l15 = lane & 15, l16 = lane >> 4;

  int srow1 = tid >> 2, srow2 = 64 + srow1;
  int kc = (tid & 3) * 8;
  int p1 = pt * BM + srow1, p2 = pt * BM + srow2;
  const bf16* a1 = xb + (size_t)(perm[seg0 + (p1 < cnt ? p1 : 0)] >> 1) * H_DIM + kc;
  const bf16* a2 = xb + (size_t)(perm[seg0 + (p2 < cnt ? p2 : 0)] >> 1) * H_DIM + kc;
  const bf16* g1 = WgT + ((size_t)e * I_DIM + n0 + srow1) * H_DIM + kc;
  const bf16* g2 = WgT + ((size_t)e * I_DIM + n0 + srow2) * H_DIM + kc;
  const bf16* u1 = WuT + ((size_t)e * I_DIM + n0 + srow1) * H_DIM + kc;
  const bf16* u2 = WuT + ((size_t)e * I_DIM + n0 + srow2) * H_DIM + kc;
  bf16* lA1 = &As[tid * 8];       bf16* lA2 = &As[2048 + tid * 8];
  bf16* lG1 = &Bg[tid * 8];       bf16* lG2 = &Bg[2048 + tid * 8];
  bf16* lU1 = &Bu[tid * 8];       bf16* lU2 = &Bu[2048 + tid * 8];

  f32x4 accg[4][4], accu[4][4];
#pragma unroll
  for (int m = 0; m < 4; ++m)
#pragma unroll
    for (int n = 0; n < 4; ++n) {
      accg[m][n] = (f32x4){0.f, 0.f, 0.f, 0.f};
      accu[m][n] = (f32x4){0.f, 0.f, 0.f, 0.f};
    }

  for (int k0 = 0; k0 < H_DIM; k0 += 2 * BK) {
    GL16(a1 + k0, lA1);            GL16(a2 + k0, lA2);
    GL16(a1 + k0 + BK, lA1 + HTILE); GL16(a2 + k0 + BK, lA2 + HTILE);
    GL16(g1 + k0, lG1);            GL16(g2 + k0, lG2);
    GL16(g1 + k0 + BK, lG1 + HTILE); GL16(g2 + k0 + BK, lG2 + HTILE);
    GL16(u1 + k0, lU1);            GL16(u2 + k0, lU2);
    GL16(u1 + k0 + BK, lU1 + HTILE); GL16(u2 + k0 + BK, lU2 + HTILE);
    __syncthreads();               // drains vmcnt -> both halves ready

#pragma unroll
    for (int kk = 0; kk < 2; ++kk) {
      const bf16* Ab = &As[kk * HTILE];
      const bf16* Gb = &Bg[kk * HTILE];
      const bf16* Ub = &Bu[kk * HTILE];
      bf16x8 af[4], bg[4], bu[4];
#pragma unroll
      for (int m = 0; m < 4; ++m)
        af[m] = *reinterpret_cast<const bf16x8*>(&Ab[(wm * 64 + m * 16 + l15) * BK + l16 * 8]);
#pragma unroll
      for (int n = 0; n < 4; ++n) {
        bg[n] = *reinterpret_cast<const bf16x8*>(&Gb[(wn * 64 + n * 16 + l15) * BK + l16 * 8]);
        bu[n] = *reinterpret_cast<const bf16x8*>(&Ub[(wn * 64 + n * 16 + l15) * BK + l16 * 8]);
      }
#pragma unroll
      for (int m = 0; m < 4; ++m)
#pragma unroll
        for (int n = 0; n < 4; ++n) {
          accg[m][n] = __builtin_amdgcn_mfma_f32_16x16x32_bf16(af[m], bg[n], accg[m][n], 0, 0, 0);
          accu[m][n] = __builtin_amdgcn_mfma_f32_16x16x32_bf16(af[m], bu[n], accu[m][n], 0, 0, 0);
        }
    }
    __syncthreads();
  }

#pragma unroll
  for (int m = 0; m < 4; ++m) {
#pragma unroll
    for (int r = 0; r < 4; ++r) {
      int p_glob = pt * BM + wm * 64 + m * 16 + l16 * 4 + r;
      if (p_glob < cnt) {
        bf16* hrow = hidden + (size_t)(seg0 + p_glob) * I_DIM;
#pragma unroll
        for (int n = 0; n < 4; ++n) {
          int col = n0 + wn * 64 + n * 16 + l15;
          float g = accg[m][n][r];
          float u = accu[m][n][r];
          float h = g / (1.f + __expf(-g)) * u;
          hrow[col] = (bf16)h;
        }
      }
    }
  }
}

// ------- down grouped GEMM: split-K x2 bf16 partials, 4 half-tiles (K=128) per barrier -------
// LDS 64KB x 2 blocks = 128 <= 160KB: occupancy unchanged vs K=64 variant, barriers halved.
__global__ __launch_bounds__(256, 2) void k_down(const bf16* __restrict__ hidden,
                                                 const bf16* __restrict__ WdT,
                                                 const int* __restrict__ perm,
                                                 const int* __restrict__ offsets,
                                                 const int* __restrict__ tiles,
                                                 const int* __restrict__ n_tiles,
                                                 bf16* __restrict__ pair_half) {
  if ((int)blockIdx.y >= *n_tiles) return;
  int tv = tiles[blockIdx.y];
  int e = tv >> 16, pt = tv & 0xffff;
  int seg0 = offsets[e], cnt = offsets[e + 1] - seg0;
  int n0 = blockIdx.x * BN;
  int kz = blockIdx.z * (I_DIM / 2);
  bf16* pout = pair_half + (size_t)blockIdx.z * 2 * T_TOK * H_DIM;

  __shared__ bf16 As[4 * HTILE];   // 32KB: 4 half-tiles
  __shared__ bf16 Bs[4 * HTILE];

  int tid = threadIdx.x, lane = tid & 63, wid = tid >> 6;
  int wm = wid >> 1, wn = wid & 1, l15 = lane & 15, l16 = lane >> 4;

  int srow1 = tid >> 2, srow2 = 64 + srow1;
  int kc = (tid & 3) * 8;
  int p1 = pt * BM + srow1, p2 = pt * BM + srow2;
  const bf16* a1 = hidden + (size_t)(seg0 + (p1 < cnt ? p1 : 0)) * I_DIM + kz + kc;
  const bf16* a2 = hidden + (size_t)(seg0 + (p2 < cnt ? p2 : 0)) * I_DIM + kz + kc;
  const bf16* b1 = WdT + ((size_t)e * H_DIM + n0 + srow1) * I_DIM + kz + kc;
  const bf16* b2 = WdT + ((size_t)e * H_DIM + n0 + srow2) * I_DIM + kz + kc;
  bf16* lA1 = &As[tid * 8];  bf16* lA2 = &As[2048 + tid * 8];
  bf16* lB1 = &Bs[tid * 8];  bf16* lB2 = &Bs[2048 + tid * 8];

  f32x4 acc[4][4];
#pragma unroll
  for (int m = 0; m < 4; ++m)
#pragma unroll
    for (int n = 0; n < 4; ++n) acc[m][n] = (f32x4){0.f, 0.f, 0.f, 0.f};

  for (int k0 = 0; k0 < I_DIM / 2; k0 += 4 * BK) {   // 11 iterations
#pragma unroll
    for (int h = 0; h < 4; ++h) {
      GL16(a1 + k0 + h * BK, lA1 + h * HTILE);
      GL16(a2 + k0 + h * BK, lA2 + h * HTILE);
      GL16(b1 + k0 + h * BK, lB1 + h * HTILE);
      GL16(b2 + k0 + h * BK, lB2 + h * HTILE);
    }
    __syncthreads();

#pragma unroll
    for (int kk = 0; kk < 4; ++kk) {
      const bf16* Ab = &As[kk * HTILE];
      const bf16* Bb = &Bs[kk * HTILE];
      bf16x8 af[4], bfr[4];
#pragma unroll
      for (int m = 0; m < 4; ++m)
        af[m] = *reinterpret_cast<const bf16x8*>(&Ab[(wm * 64 + m * 16 + l15) * BK + l16 * 8]);
#pragma unroll
      for (int n = 0; n < 4; ++n)
        bfr[n] = *reinterpret_cast<const bf16x8*>(&Bb[(wn * 64 + n * 16 + l15) * BK + l16 * 8]);
#pragma unroll
      for (int m = 0; m < 4; ++m)
#pragma unroll
        for (int n = 0; n < 4; ++n)
          acc[m][n] = __builtin_amdgcn_mfma_f32_16x16x32_bf16(af[m], bfr[n], acc[m][n], 0, 0, 0);
    }
    __syncthreads();
  }

#pragma unroll
  for (int m = 0; m < 4; ++m) {
#pragma unroll
    for (int r = 0; r < 4; ++r) {
      int p_glob = pt * BM + wm * 64 + m * 16 + l16 * 4 + r;
      if (p_glob < cnt) {
        int pair = perm[seg0 + p_glob];
        bf16* orow = pout + (size_t)pair * H_DIM;
#pragma unroll
        for (int n = 0; n < 4; ++n) {
          int col = n0 + wn * 64 + n * 16 + l15;
          orow[col] = (bf16)acc[m][n][r];
        }
      }
    }
  }
}

// ------- combine: out[t] = w0*(z0[2t]+z1[2t]) + w1*(z0[2t+1]+z1[2t+1]) -------
__global__ __launch_bounds__(256) void k_combine(const bf16* __restrict__ pair_half,
                                                 const float* __restrict__ rw,
                                                 float* __restrict__ out) {
  int t = blockIdx.x;
  int c = threadIdx.x;
  const bf16* z0 = pair_half;
  const bf16* z1 = pair_half + (size_t)2 * T_TOK * H_DIM;
  float w0 = rw[2 * t];
  float w1 = rw[2 * t + 1];
  size_t r0 = (size_t)(2 * t) * H_DIM + c * 4;
  size_t r1 = (size_t)(2 * t + 1) * H_DIM + c * 4;
  bf16x4 a0 = *reinterpret_cast<const bf16x4*>(z0 + r0);
  bf16x4 a1 = *reinterpret_cast<const bf16x4*>(z1 + r0);
  bf16x4 b0 = *reinterpret_cast<const bf16x4*>(z0 + r1);
  bf16x4 b1 = *reinterpret_cast<const bf16x4*>(z1 + r1);
  float4 o;
  o.x = w0 * ((float)a0[0] + (float)a1[0]) + w1 * ((float)b0[0] + (float)b1[0]);
  o.y = w0 * ((float)a0[1] + (float)a1[1]) + w1 * ((float)b0[1] + (float)b1[1]);
  o.z = w0 * ((float)a0[2] + (float)a1[2]) + w1 * ((float)b0[2] + (float)b1[2]);
  o.w = w0 * ((float)a0[3] + (float)a1[3]) + w1 * ((float)b0[3] + (float)b1[3]);
  *reinterpret_cast<float4*>(out + (size_t)t * H_DIM + c * 4) = o;
}

extern "C" void kernel_launch(void* const* d_in, const int* in_sizes, int n_in,
                              void* d_out, int out_size, void* d_ws, size_t ws_size,
                              hipStream_t stream) {
  const float* x  = (const float*)d_in[0];
  const float* Wr = (const float*)d_in[1];
  const float* Wg = (const float*)d_in[2];
  const float* Wu = (const float*)d_in[3];
  const float* Wd = (const float*)d_in[4];
  float* out = (float*)d_out;

  char* ws = (char*)d_ws;
  int*   counts  = (int*)(ws);
  int*   cursor  = (int*)(ws + 256);
  int*   offsets = (int*)(ws + 512);
  int*   n_tiles = (int*)(ws + 768);
  int*   tiles   = (int*)(ws + 1024);
  int*   ridx    = (int*)(ws + 64 * 1024);
  float* rw      = (float*)(ws + 128 * 1024);
  int*   perm    = (int*)(ws + 192 * 1024);
  bf16*  xb      = (bf16*)(ws + (1ull << 20));
  bf16*  WgT     = (bf16*)(ws + (16ull << 20));
  bf16*  WuT     = (bf16*)(ws + (66ull << 20));
  bf16*  WdT     = (bf16*)(ws + (116ull << 20));
  bf16*  hidden  = (bf16*)(ws + (166ull << 20));
  bf16*  pair_half = (bf16*)(ws + (212ull << 20));   // [2][8192][1024] bf16 = 32 MiB

  hipMemsetAsync(counts, 0, 64, stream);
  k_xcast<<<dim3(T_TOK * H_DIM / 2048), dim3(256), 0, stream>>>(x, xb);
  k_transpose_gu<<<dim3(I_DIM / 64, H_DIM / 64, 2 * E_NUM), dim3(256), 0, stream>>>(
      Wg, Wu, WgT, WuT);
  k_transpose_d<<<dim3(H_DIM / 64, I_DIM / 64, E_NUM), dim3(256), 0, stream>>>(Wd, WdT);
  k_router<<<dim3(T_TOK / 4), dim3(256), 0, stream>>>(x, Wr, ridx, rw, counts);
  k_scan<<<dim3(1), dim3(64), 0, stream>>>(counts, offsets, cursor, tiles, n_tiles);
  k_scatter<<<dim3((T_TOK + 255) / 256), dim3(256), 0, stream>>>(ridx, offsets, cursor, perm);
  k_gateup<<<dim3(I_DIM / BN, MAXTILE), dim3(256), 0, stream>>>(
      xb, WgT, WuT, perm, offsets, tiles, n_tiles, hidden);
  k_down<<<dim3(H_DIM / BN, MAXTILE, 2), dim3(256), 0, stream>>>(
      hidden, WdT, perm, offsets, tiles, n_tiles, pair_half);
  k_combine<<<dim3(T_TOK), dim3(256), 0, stream>>>(pair_half, rw, out);
}

// Round 16
// 456.236 us; speedup vs baseline: 1.4274x; 1.0467x over previous
//
#include <hip/hip_runtime.h>
#include <cstdint>
#include <cstddef>

#define T_TOK 4096
#define H_DIM 1024
#define I_DIM 2816
#define E_NUM 9
#define MAXTILE 76

typedef __bf16 bf16;
typedef bf16 bf16x4 __attribute__((ext_vector_type(4)));
typedef bf16 bf16x8 __attribute__((ext_vector_type(8)));
typedef float f32x4 __attribute__((ext_vector_type(4)));

constexpr int BM = 128, BN = 128, BK = 32;
constexpr int HTILE = BM * BK;          // 4096 elems = 8KB per half
constexpr size_t HI = (size_t)H_DIM * I_DIM;

// prepass mega-kernel block ranges
constexpr int XCAST_BLKS  = T_TOK * H_DIM / 2048;                    // 2048
constexpr int TGU_BLKS    = (I_DIM / 64) * (H_DIM / 64) * 2 * E_NUM; // 12672
constexpr int TD_BLKS     = (H_DIM / 64) * (I_DIM / 64) * E_NUM;     // 6336
constexpr int ROUTER_BLKS = T_TOK / 4;                               // 1024
constexpr int PRE_BLKS    = XCAST_BLKS + TGU_BLKS + TD_BLKS + ROUTER_BLKS;

// async global->LDS, 16B per lane; LDS dest must be linear (wave-uniform base + lane*16)
#define GL16(gp, lp)                                                                   \
  __builtin_amdgcn_global_load_lds((const __attribute__((address_space(1))) void*)(gp), \
                                   (__attribute__((address_space(3))) void*)(lp), 16, 0, 0)

// ------- transpose+convert core: one 64x64 tile, vectorized 16B writes -------
__device__ __forceinline__ void transpose_tile(const float* __restrict__ src,
                                               bf16* __restrict__ dst, int R, int C,
                                               int bx, int by) {
  __shared__ bf16 tile[64][68];
  int r0 = by * 64, c0 = bx * 64;
  int t = threadIdx.x;
  int tr = t >> 4, tc = (t & 15) * 4;
#pragma unroll
  for (int it = 0; it < 4; ++it) {
    int r = tr + it * 16;
    float4 v = *reinterpret_cast<const float4*>(src + (size_t)(r0 + r) * C + c0 + tc);
    bf16x4 w; w[0]=(bf16)v.x; w[1]=(bf16)v.y; w[2]=(bf16)v.z; w[3]=(bf16)v.w;
    *reinterpret_cast<bf16x4*>(&tile[r][tc]) = w;
  }
  __syncthreads();
  int oc = t >> 2;
  int q  = t & 3;
  bf16x8 w0, w1;
#pragma unroll
  for (int j = 0; j < 8; ++j) w0[j] = tile[q * 16 + j][oc];
#pragma unroll
  for (int j = 0; j < 8; ++j) w1[j] = tile[q * 16 + 8 + j][oc];
  bf16* dp = dst + (size_t)(c0 + oc) * R + r0 + q * 16;
  *reinterpret_cast<bf16x8*>(dp)     = w0;
  *reinterpret_cast<bf16x8*>(dp + 8) = w1;
}

// ------- fused prepass: xcast | transpose Wg/Wu | transpose Wd | router -------
// All four phases are mutually independent; one launch removes 3 gaps and lets
// tails of one phase overlap heads of the next across CUs.
__global__ __launch_bounds__(256) void k_prepass(const float* __restrict__ x,
                                                 bf16* __restrict__ xb,
                                                 const float* __restrict__ Wg,
                                                 const float* __restrict__ Wu,
                                                 const float* __restrict__ Wd,
                                                 bf16* __restrict__ WgT,
                                                 bf16* __restrict__ WuT,
                                                 bf16* __restrict__ WdT,
                                                 const float* __restrict__ Wr,
                                                 int* __restrict__ ridx,
                                                 float* __restrict__ rw,
                                                 int* __restrict__ counts) {
  int b = blockIdx.x;

  if (b < XCAST_BLKS) {                       // ---- x: fp32 -> bf16 ----
    size_t i = ((size_t)b * 256 + threadIdx.x) * 8;
    float4 a = *reinterpret_cast<const float4*>(x + i);
    float4 c = *reinterpret_cast<const float4*>(x + i + 4);
    bf16x8 v;
    v[0]=(bf16)a.x; v[1]=(bf16)a.y; v[2]=(bf16)a.z; v[3]=(bf16)a.w;
    v[4]=(bf16)c.x; v[5]=(bf16)c.y; v[6]=(bf16)c.z; v[7]=(bf16)c.w;
    *reinterpret_cast<bf16x8*>(xb + i) = v;
    return;
  }
  b -= XCAST_BLKS;

  if (b < TGU_BLKS) {                         // ---- Wg/Wu transpose [H][I]->[I][H] ----
    int bx = b % (I_DIM / 64);
    int rest = b / (I_DIM / 64);
    int by = rest % (H_DIM / 64);
    int z  = rest / (H_DIM / 64);             // [0,18)
    const float* src = (z < 9) ? (Wg + (size_t)z * HI) : (Wu + (size_t)(z - 9) * HI);
    bf16* dst = (z < 9) ? (WgT + (size_t)z * HI) : (WuT + (size_t)(z - 9) * HI);
    transpose_tile(src, dst, H_DIM, I_DIM, bx, by);
    return;
  }
  b -= TGU_BLKS;

  if (b < TD_BLKS) {                          // ---- Wd transpose [I][H]->[H][I] ----
    int bx = b % (H_DIM / 64);
    int rest = b / (H_DIM / 64);
    int by = rest % (I_DIM / 64);
    int z  = rest / (I_DIM / 64);             // [0,9)
    transpose_tile(Wd + (size_t)z * HI, WdT + (size_t)z * HI, I_DIM, H_DIM, bx, by);
    return;
  }
  b -= TD_BLKS;

  // ---- router: fp32 logits, softmax top-2, renormalized (identical math) ----
  {
    int lane = threadIdx.x & 63;
    int wid  = threadIdx.x >> 6;
    int t = b * 4 + wid;
    const float* xr = x + (size_t)t * H_DIM;
    float acc[E_NUM];
#pragma unroll
    for (int e = 0; e < E_NUM; ++e) acc[e] = 0.f;
    for (int h = lane; h < H_DIM; h += 64) {
      float xv = xr[h];
      const float* wr = Wr + h * E_NUM;
#pragma unroll
      for (int e = 0; e < E_NUM; ++e) acc[e] += xv * wr[e];
    }
#pragma unroll
    for (int off = 32; off > 0; off >>= 1) {
#pragma unroll
      for (int e = 0; e < E_NUM; ++e) acc[e] += __shfl_xor(acc[e], off);
    }
    if (lane == 0) {
      int i0 = 0;
#pragma unroll
      for (int e = 1; e < E_NUM; ++e) if (acc[e] > acc[i0]) i0 = e;
      int i1 = (i0 == 0) ? 1 : 0;
#pragma unroll
      for (int e = 0; e < E_NUM; ++e) if (e != i0 && acc[e] > acc[i1]) i1 = e;
      float r  = expf(acc[i1] - acc[i0]);
      float w0 = 1.f / (1.f + r);
      float w1 = r / (1.f + r);
      ridx[2 * t]     = i0;
      ridx[2 * t + 1] = i1;
      rw[2 * t]     = w0;
      rw[2 * t + 1] = w1;
      atomicAdd(&counts[i0], 1);
      atomicAdd(&counts[i1], 1);
    }
  }
}

// ------- scan: counts -> offsets, compact tile list, zero cursors -------
__global__ void k_scan(const int* __restrict__ counts, int* __restrict__ offsets,
                       int* __restrict__ cursor, int* __restrict__ tiles,
                       int* __restrict__ n_tiles) {
  if (threadIdx.x == 0) {
    int s = 0, nt = 0;
    for (int e = 0; e < E_NUM; ++e) {
      offsets[e] = s;
      int c = counts[e];
      for (int pt = 0; pt * BM < c && nt < MAXTILE; ++pt) tiles[nt++] = (e << 16) | pt;
      s += c;
    }
    offsets[E_NUM] = s;
    *n_tiles = nt;
  }
  if (threadIdx.x < E_NUM) cursor[threadIdx.x] = 0;
}

// ---------------- scatter pair ids into expert-sorted perm ----------------
__global__ __launch_bounds__(256) void k_scatter(const int* __restrict__ ridx,
                                                 const int* __restrict__ offsets,
                                                 int* __restrict__ cursor,
                                                 int* __restrict__ perm) {
  int t = blockIdx.x * 256 + threadIdx.x;
  if (t >= T_TOK) return;
#pragma unroll
  for (int k = 0; k < 2; ++k) {
    int e = ridx[2 * t + k];
    int pos = atomicAdd(&cursor[e], 1);
    perm[offsets[e] + pos] = 2 * t + k;
  }
}

// ------- fused gate+up grouped GEMM: BK=64/barrier-pair, (256,2) proven (146us) -------
// NOTE: (256,2) is the occupancy cliff edge — (256,3) and (256,4) both spill the
// 128-reg accumulator to scratch (R8: 4.2GB, R14: 554MB writes). Do not raise.
__global__ __launch_bounds__(256, 2) void k_gateup(const bf16* __restrict__ xb,
                                                   const bf16* __restrict__ WgT,
                                                   const bf16* __restrict__ WuT,
                                                   const int* __restrict__ perm,
                                                   const int* __restrict__ offsets,
                                                   const int* __restrict__ tiles,
                                                   const int* __restrict__ n_tiles,
                                                   bf16* __restrict__ hidden) {
  if ((int)blockIdx.y >= *n_tiles) return;
  int tv = tiles[blockIdx.y];
  int e = tv >> 16, pt = tv & 0xffff;
  int seg0 = offsets[e], cnt = offsets[e + 1] - seg0;
  int n0 = blockIdx.x * BN;

  __shared__ bf16 As[2 * HTILE];   // halves at 0, HTILE
  __shared__ bf16 Bg[2 * HTILE];
  __shared__ bf16 Bu[2 * HTILE];

  int tid = threadIdx.x, lane = tid & 63, wid = tid >> 6;
  int wm = wid >> 1, wn = wid & 1, l15 = lane & 15, l16 = lane >> 4;

  int srow1 = tid >> 2, srow2 = 64 + srow1;
  int kc = (tid & 3) * 8;
  int p1 = pt * BM + srow1, p2 = pt * BM + srow2;
  const bf16* a1 = xb + (size_t)(perm[seg0 + (p1 < cnt ? p1 : 0)] >> 1) * H_DIM + kc;
  const bf16* a2 = xb + (size_t)(perm[seg0 + (p2 < cnt ? p2 : 0)] >> 1) * H_DIM + kc;
  const bf16* g1 = WgT + ((size_t)e * I_DIM + n0 + srow1) * H_DIM + kc;
  const bf16* g2 = WgT + ((size_t)e * I_DIM + n0 + srow2) * H_DIM + kc;
  const bf16* u1 = WuT + ((size_t)e * I_DIM + n0 + srow1) * H_DIM + kc;
  const bf16* u2 = WuT + ((size_t)e * I_DIM + n0 + srow2) * H_DIM + kc;
  bf16* lA1 = &As[tid * 8];       bf16* lA2 = &As[2048 + tid * 8];
  bf16* lG1 = &Bg[tid * 8];       bf16* lG2 = &Bg[2048 + tid * 8];
  bf16* lU1 = &Bu[tid * 8];       bf16* lU2 = &Bu[2048 + tid * 8];

  f32x4 accg[4][4], accu[4][4];
#pragma unroll
  for (int m = 0; m < 4; ++m)
#pragma unroll
    for (int n = 0; n < 4; ++n) {
      accg[m][n] = (f32x4){0.f, 0.f, 0.f, 0.f};
      accu[m][n] = (f32x4){0.f, 0.f, 0.f, 0.f};
    }

  for (int k0 = 0; k0 < H_DIM; k0 += 2 * BK) {
    GL16(a1 + k0, lA1);            GL16(a2 + k0, lA2);
    GL16(a1 + k0 + BK, lA1 + HTILE); GL16(a2 + k0 + BK, lA2 + HTILE);
    GL16(g1 + k0, lG1);            GL16(g2 + k0, lG2);
    GL16(g1 + k0 + BK, lG1 + HTILE); GL16(g2 + k0 + BK, lG2 + HTILE);
    GL16(u1 + k0, lU1);            GL16(u2 + k0, lU2);
    GL16(u1 + k0 + BK, lU1 + HTILE); GL16(u2 + k0 + BK, lU2 + HTILE);
    __syncthreads();               // drains vmcnt -> both halves ready

#pragma unroll
    for (int kk = 0; kk < 2; ++kk) {
      const bf16* Ab = &As[kk * HTILE];
      const bf16* Gb = &Bg[kk * HTILE];
      const bf16* Ub = &Bu[kk * HTILE];
      bf16x8 af[4], bg[4], bu[4];
#pragma unroll
      for (int m = 0; m < 4; ++m)
        af[m] = *reinterpret_cast<const bf16x8*>(&Ab[(wm * 64 + m * 16 + l15) * BK + l16 * 8]);
#pragma unroll
      for (int n = 0; n < 4; ++n) {
        bg[n] = *reinterpret_cast<const bf16x8*>(&Gb[(wn * 64 + n * 16 + l15) * BK + l16 * 8]);
        bu[n] = *reinterpret_cast<const bf16x8*>(&Ub[(wn * 64 + n * 16 + l15) * BK + l16 * 8]);
      }
#pragma unroll
      for (int m = 0; m < 4; ++m)
#pragma unroll
        for (int n = 0; n < 4; ++n) {
          accg[m][n] = __builtin_amdgcn_mfma_f32_16x16x32_bf16(af[m], bg[n], accg[m][n], 0, 0, 0);
          accu[m][n] = __builtin_amdgcn_mfma_f32_16x16x32_bf16(af[m], bu[n], accu[m][n], 0, 0, 0);
        }
    }
    __syncthreads();
  }

#pragma unroll
  for (int m = 0; m < 4; ++m) {
#pragma unroll
    for (int r = 0; r < 4; ++r) {
      int p_glob = pt * BM + wm * 64 + m * 16 + l16 * 4 + r;
      if (p_glob < cnt) {
        bf16* hrow = hidden + (size_t)(seg0 + p_glob) * I_DIM;
#pragma unroll
        for (int n = 0; n < 4; ++n) {
          int col = n0 + wn * 64 + n * 16 + l15;
          float g = accg[m][n][r];
          float u = accu[m][n][r];
          float h = g / (1.f + __expf(-g)) * u;
          hrow[col] = (bf16)h;
        }
      }
    }
  }
}

// ------- down grouped GEMM: split-K x2 bf16 partials, K=64/barrier (R13 proven) -------
__global__ __launch_bounds__(256, 2) void k_down(const bf16* __restrict__ hidden,
                                                 const bf16* __restrict__ WdT,
                                                 const int* __restrict__ perm,
                                                 const int* __restrict__ offsets,
                                                 const int* __restrict__ tiles,
                                                 const int* __restrict__ n_tiles,
                                                 bf16* __restrict__ pair_half) {
  if ((int)blockIdx.y >= *n_tiles) return;
  int tv = tiles[blockIdx.y];
  int e = tv >> 16, pt = tv & 0xffff;
  int seg0 = offsets[e], cnt = offsets[e + 1] - seg0;
  int n0 = blockIdx.x * BN;
  int kz = blockIdx.z * (I_DIM / 2);
  bf16* pout = pair_half + (size_t)blockIdx.z * 2 * T_TOK * H_DIM;

  __shared__ bf16 As[2 * HTILE];
  __shared__ bf16 Bs[2 * HTILE];

  int tid = threadIdx.x, lane = tid & 63, wid = tid >> 6;
  int wm = wid >> 1, wn = wid & 1, l15 = lane & 15, l16 = lane >> 4;

  int srow1 = tid >> 2, srow2 = 64 + srow1;
  int kc = (tid & 3) * 8;
  int p1 = pt * BM + srow1, p2 = pt * BM + srow2;
  const bf16* a1 = hidden + (size_t)(seg0 + (p1 < cnt ? p1 : 0)) * I_DIM + kz + kc;
  const bf16* a2 = hidden + (size_t)(seg0 + (p2 < cnt ? p2 : 0)) * I_DIM + kz + kc;
  const bf16* b1 = WdT + ((size_t)e * H_DIM + n0 + srow1) * I_DIM + kz + kc;
  const bf16* b2 = WdT + ((size_t)e * H_DIM + n0 + srow2) * I_DIM + kz + kc;
  bf16* lA1 = &As[tid * 8];  bf16* lA2 = &As[2048 + tid * 8];
  bf16* lB1 = &Bs[tid * 8];  bf16* lB2 = &Bs[2048 + tid * 8];

  f32x4 acc[4][4];
#pragma unroll
  for (int m = 0; m < 4; ++m)
#pragma unroll
    for (int n = 0; n < 4; ++n) acc[m][n] = (f32x4){0.f, 0.f, 0.f, 0.f};

  for (int k0 = 0; k0 < I_DIM / 2; k0 += 2 * BK) {
    GL16(a1 + k0, lA1);            GL16(a2 + k0, lA2);
    GL16(a1 + k0 + BK, lA1 + HTILE); GL16(a2 + k0 + BK, lA2 + HTILE);
    GL16(b1 + k0, lB1);            GL16(b2 + k0, lB2);
    GL16(b1 + k0 + BK, lB1 + HTILE); GL16(b2 + k0 + BK, lB2 + HTILE);
    __syncthreads();

#pragma unroll
    for (int kk = 0; kk < 2; ++kk) {
      const bf16* Ab = &As[kk * HTILE];
      const bf16* Bb = &Bs[kk * HTILE];
      bf16x8 af[4], bfr[4];
#pragma unroll
      for (int m = 0; m < 4; ++m)
        af[m] = *reinterpret_cast<const bf16x8*>(&Ab[(wm * 64 + m * 16 + l15) * BK + l16 * 8]);
#pragma unroll
      for (int n = 0; n < 4; ++n)
        bfr[n] = *reinterpret_cast<const bf16x8*>(&Bb[(wn * 64 + n * 16 + l15) * BK + l16 * 8]);
#pragma unroll
      for (int m = 0; m < 4; ++m)
#pragma unroll
        for (int n = 0; n < 4; ++n)
          acc[m][n] = __builtin_amdgcn_mfma_f32_16x16x32_bf16(af[m], bfr[n], acc[m][n], 0, 0, 0);
    }
    __syncthreads();
  }

#pragma unroll
  for (int m = 0; m < 4; ++m) {
#pragma unroll
    for (int r = 0; r < 4; ++r) {
      int p_glob = pt * BM + wm * 64 + m * 16 + l16 * 4 + r;
      if (p_glob < cnt) {
        int pair = perm[seg0 + p_glob];
        bf16* orow = pout + (size_t)pair * H_DIM;
#pragma unroll
        for (int n = 0; n < 4; ++n) {
          int col = n0 + wn * 64 + n * 16 + l15;
          orow[col] = (bf16)acc[m][n][r];
        }
      }
    }
  }
}

// ------- combine: out[t] = w0*(z0[2t]+z1[2t]) + w1*(z0[2t+1]+z1[2t+1]) -------
__global__ __launch_bounds__(256) void k_combine(const bf16* __restrict__ pair_half,
                                                 const float* __restrict__ rw,
                                                 float* __restrict__ out) {
  int t = blockIdx.x;
  int c = threadIdx.x;
  const bf16* z0 = pair_half;
  const bf16* z1 = pair_half + (size_t)2 * T_TOK * H_DIM;
  float w0 = rw[2 * t];
  float w1 = rw[2 * t + 1];
  size_t r0 = (size_t)(2 * t) * H_DIM + c * 4;
  size_t r1 = (size_t)(2 * t + 1) * H_DIM + c * 4;
  bf16x4 a0 = *reinterpret_cast<const bf16x4*>(z0 + r0);
  bf16x4 a1 = *reinterpret_cast<const bf16x4*>(z1 + r0);
  bf16x4 b0 = *reinterpret_cast<const bf16x4*>(z0 + r1);
  bf16x4 b1 = *reinterpret_cast<const bf16x4*>(z1 + r1);
  float4 o;
  o.x = w0 * ((float)a0[0] + (float)a1[0]) + w1 * ((float)b0[0] + (float)b1[0]);
  o.y = w0 * ((float)a0[1] + (float)a1[1]) + w1 * ((float)b0[1] + (float)b1[1]);
  o.z = w0 * ((float)a0[2] + (float)a1[2]) + w1 * ((float)b0[2] + (float)b1[2]);
  o.w = w0 * ((float)a0[3] + (float)a1[3]) + w1 * ((float)b0[3] + (float)b1[3]);
  *reinterpret_cast<float4*>(out + (size_t)t * H_DIM + c * 4) = o;
}

extern "C" void kernel_launch(void* const* d_in, const int* in_sizes, int n_in,
                              void* d_out, int out_size, void* d_ws, size_t ws_size,
                              hipStream_t stream) {
  const float* x  = (const float*)d_in[0];
  const float* Wr = (const float*)d_in[1];
  const float* Wg = (const float*)d_in[2];
  const float* Wu = (const float*)d_in[3];
  const float* Wd = (const float*)d_in[4];
  float* out = (float*)d_out;

  char* ws = (char*)d_ws;
  int*   counts  = (int*)(ws);
  int*   cursor  = (int*)(ws + 256);
  int*   offsets = (int*)(ws + 512);
  int*   n_tiles = (int*)(ws + 768);
  int*   tiles   = (int*)(ws + 1024);
  int*   ridx    = (int*)(ws + 64 * 1024);
  float* rw      = (float*)(ws + 128 * 1024);
  int*   perm    = (int*)(ws + 192 * 1024);
  bf16*  xb      = (bf16*)(ws + (1ull << 20));
  bf16*  WgT     = (bf16*)(ws + (16ull << 20));
  bf16*  WuT     = (bf16*)(ws + (66ull << 20));
  bf16*  WdT     = (bf16*)(ws + (116ull << 20));
  bf16*  hidden  = (bf16*)(ws + (166ull << 20));
  bf16*  pair_half = (bf16*)(ws + (212ull << 20));   // [2][8192][1024] bf16 = 32 MiB

  hipMemsetAsync(counts, 0, 64, stream);
  k_prepass<<<dim3(PRE_BLKS), dim3(256), 0, stream>>>(
      x, xb, Wg, Wu, Wd, WgT, WuT, WdT, Wr, ridx, rw, counts);
  k_scan<<<dim3(1), dim3(64), 0, stream>>>(counts, offsets, cursor, tiles, n_tiles);
  k_scatter<<<dim3((T_TOK + 255) / 256), dim3(256), 0, stream>>>(ridx, offsets, cursor, perm);
  k_gateup<<<dim3(I_DIM / BN, MAXTILE), dim3(256), 0, stream>>>(
      xb, WgT, WuT, perm, offsets, tiles, n_tiles, hidden);
  k_down<<<dim3(H_DIM / BN, MAXTILE, 2), dim3(256), 0, stream>>>(
      hidden, WdT, perm, offsets, tiles, n_tiles, pair_half);
  k_combine<<<dim3(T_TOK), dim3(256), 0, stream>>>(pair_half, rw, out);
}

// Round 17
// 454.503 us; speedup vs baseline: 1.4328x; 1.0038x over previous
//
#include <hip/hip_runtime.h>
#include <cstdint>
#include <cstddef>

#define T_TOK 4096
#define H_DIM 1024
#define I_DIM 2816
#define E_NUM 9
#define MAXTILE 76

typedef __bf16 bf16;
typedef bf16 bf16x4 __attribute__((ext_vector_type(4)));
typedef bf16 bf16x8 __attribute__((ext_vector_type(8)));
typedef float f32x4 __attribute__((ext_vector_type(4)));

constexpr int BM = 128, BN = 128, BK = 32;
constexpr int HTILE = BM * BK;          // 4096 elems = 8KB per half
constexpr size_t HI = (size_t)H_DIM * I_DIM;

// prepass mega-kernel block ranges
constexpr int XCAST_BLKS  = T_TOK * H_DIM / 2048;                    // 2048
constexpr int TGU_BLKS    = (I_DIM / 64) * (H_DIM / 64) * 2 * E_NUM; // 12672
constexpr int TD_BLKS     = (H_DIM / 64) * (I_DIM / 64) * E_NUM;     // 6336
constexpr int ROUTER_BLKS = T_TOK / 4;                               // 1024
constexpr int PRE_BLKS    = XCAST_BLKS + TGU_BLKS + TD_BLKS + ROUTER_BLKS;

// async global->LDS, 16B per lane; LDS dest must be linear (wave-uniform base + lane*16)
#define GL16(gp, lp)                                                                   \
  __builtin_amdgcn_global_load_lds((const __attribute__((address_space(1))) void*)(gp), \
                                   (__attribute__((address_space(3))) void*)(lp), 16, 0, 0)

// ------- transpose+convert core: GL16-staged fp32 tile, vectorized bf16 writes -------
// Load phase is DMA (no VGPR round-trip, no serial load chain — R16's prepass ran at
// 792 GB/s because 16-VGPR regalloc serialized the float4 loads). Read phase: 16x
// ds_read_b32 (4-way conflict, cheap), convert, 2x16B coalesced global stores.
__device__ __forceinline__ void transpose_tile(const float* __restrict__ src,
                                               bf16* __restrict__ dst, int R, int C,
                                               int bx, int by) {
  __shared__ float tile[64 * 64];          // 16 KB fp32
  int r0 = by * 64, c0 = bx * 64;
  int t = threadIdx.x;
#pragma unroll
  for (int h = 0; h < 4; ++h) {
    int idx = h * 256 + t;                 // 16B chunk id; 16 chunks per 64-float row
    int row = idx >> 4;
    int col = (idx & 15) * 4;
    GL16(src + (size_t)(r0 + row) * C + c0 + col, &tile[idx * 4]);
  }
  __syncthreads();                         // drains vmcnt -> tile resident
  int oc = t >> 2;                         // [0,64) output column
  int q  = t & 3;                          // row quarter
  bf16x8 w0, w1;
#pragma unroll
  for (int j = 0; j < 8; ++j) w0[j] = (bf16)tile[(q * 16 + j) * 64 + oc];
#pragma unroll
  for (int j = 0; j < 8; ++j) w1[j] = (bf16)tile[(q * 16 + 8 + j) * 64 + oc];
  bf16* dp = dst + (size_t)(c0 + oc) * R + r0 + q * 16;
  *reinterpret_cast<bf16x8*>(dp)     = w0;
  *reinterpret_cast<bf16x8*>(dp + 8) = w1;
}

// ------- fused prepass: xcast | transpose Wg/Wu | transpose Wd | router -------
__global__ __launch_bounds__(256) void k_prepass(const float* __restrict__ x,
                                                 bf16* __restrict__ xb,
                                                 const float* __restrict__ Wg,
                                                 const float* __restrict__ Wu,
                                                 const float* __restrict__ Wd,
                                                 bf16* __restrict__ WgT,
                                                 bf16* __restrict__ WuT,
                                                 bf16* __restrict__ WdT,
                                                 const float* __restrict__ Wr,
                                                 int* __restrict__ ridx,
                                                 float* __restrict__ rw,
                                                 int* __restrict__ counts) {
  int b = blockIdx.x;

  if (b < XCAST_BLKS) {                       // ---- x: fp32 -> bf16 ----
    size_t i = ((size_t)b * 256 + threadIdx.x) * 8;
    float4 a = *reinterpret_cast<const float4*>(x + i);
    float4 c = *reinterpret_cast<const float4*>(x + i + 4);
    bf16x8 v;
    v[0]=(bf16)a.x; v[1]=(bf16)a.y; v[2]=(bf16)a.z; v[3]=(bf16)a.w;
    v[4]=(bf16)c.x; v[5]=(bf16)c.y; v[6]=(bf16)c.z; v[7]=(bf16)c.w;
    *reinterpret_cast<bf16x8*>(xb + i) = v;
    return;
  }
  b -= XCAST_BLKS;

  if (b < TGU_BLKS) {                         // ---- Wg/Wu transpose [H][I]->[I][H] ----
    int bx = b % (I_DIM / 64);
    int rest = b / (I_DIM / 64);
    int by = rest % (H_DIM / 64);
    int z  = rest / (H_DIM / 64);             // [0,18)
    const float* src = (z < 9) ? (Wg + (size_t)z * HI) : (Wu + (size_t)(z - 9) * HI);
    bf16* dst = (z < 9) ? (WgT + (size_t)z * HI) : (WuT + (size_t)(z - 9) * HI);
    transpose_tile(src, dst, H_DIM, I_DIM, bx, by);
    return;
  }
  b -= TGU_BLKS;

  if (b < TD_BLKS) {                          // ---- Wd transpose [I][H]->[H][I] ----
    int bx = b % (H_DIM / 64);
    int rest = b / (H_DIM / 64);
    int by = rest % (I_DIM / 64);
    int z  = rest / (I_DIM / 64);             // [0,9)
    transpose_tile(Wd + (size_t)z * HI, WdT + (size_t)z * HI, I_DIM, H_DIM, bx, by);
    return;
  }
  b -= TD_BLKS;

  // ---- router: fp32 logits, softmax top-2, renormalized (identical math) ----
  {
    int lane = threadIdx.x & 63;
    int wid  = threadIdx.x >> 6;
    int t = b * 4 + wid;
    const float* xr = x + (size_t)t * H_DIM;
    float acc[E_NUM];
#pragma unroll
    for (int e = 0; e < E_NUM; ++e) acc[e] = 0.f;
    for (int h = lane; h < H_DIM; h += 64) {
      float xv = xr[h];
      const float* wr = Wr + h * E_NUM;
#pragma unroll
      for (int e = 0; e < E_NUM; ++e) acc[e] += xv * wr[e];
    }
#pragma unroll
    for (int off = 32; off > 0; off >>= 1) {
#pragma unroll
      for (int e = 0; e < E_NUM; ++e) acc[e] += __shfl_xor(acc[e], off);
    }
    if (lane == 0) {
      int i0 = 0;
#pragma unroll
      for (int e = 1; e < E_NUM; ++e) if (acc[e] > acc[i0]) i0 = e;
      int i1 = (i0 == 0) ? 1 : 0;
#pragma unroll
      for (int e = 0; e < E_NUM; ++e) if (e != i0 && acc[e] > acc[i1]) i1 = e;
      float r  = expf(acc[i1] - acc[i0]);
      float w0 = 1.f / (1.f + r);
      float w1 = r / (1.f + r);
      ridx[2 * t]     = i0;
      ridx[2 * t + 1] = i1;
      rw[2 * t]     = w0;
      rw[2 * t + 1] = w1;
      atomicAdd(&counts[i0], 1);
      atomicAdd(&counts[i1], 1);
    }
  }
}

// ------- scan: counts -> offsets, compact tile list, zero cursors -------
__global__ void k_scan(const int* __restrict__ counts, int* __restrict__ offsets,
                       int* __restrict__ cursor, int* __restrict__ tiles,
                       int* __restrict__ n_tiles) {
  if (threadIdx.x == 0) {
    int s = 0, nt = 0;
    for (int e = 0; e < E_NUM; ++e) {
      offsets[e] = s;
      int c = counts[e];
      for (int pt = 0; pt * BM < c && nt < MAXTILE; ++pt) tiles[nt++] = (e << 16) | pt;
      s += c;
    }
    offsets[E_NUM] = s;
    *n_tiles = nt;
  }
  if (threadIdx.x < E_NUM) cursor[threadIdx.x] = 0;
}

// ---------------- scatter pair ids into expert-sorted perm ----------------
__global__ __launch_bounds__(256) void k_scatter(const int* __restrict__ ridx,
                                                 const int* __restrict__ offsets,
                                                 int* __restrict__ cursor,
                                                 int* __restrict__ perm) {
  int t = blockIdx.x * 256 + threadIdx.x;
  if (t >= T_TOK) return;
#pragma unroll
  for (int k = 0; k < 2; ++k) {
    int e = ridx[2 * t + k];
    int pos = atomicAdd(&cursor[e], 1);
    perm[offsets[e] + pos] = 2 * t + k;
  }
}

// ------- fused gate+up grouped GEMM: BK=64/barrier-pair, (256,2) proven (146us) -------
// NOTE: (256,2) is the occupancy cliff edge — (256,3) and (256,4) both spill the
// 128-reg accumulator to scratch (R8: 4.2GB, R14: 554MB writes). Do not raise.
__global__ __launch_bounds__(256, 2) void k_gateup(const bf16* __restrict__ xb,
                                                   const bf16* __restrict__ WgT,
                                                   const bf16* __restrict__ WuT,
                                                   const int* __restrict__ perm,
                                                   const int* __restrict__ offsets,
                                                   const int* __restrict__ tiles,
                                                   const int* __restrict__ n_tiles,
                                                   bf16* __restrict__ hidden) {
  if ((int)blockIdx.y >= *n_tiles) return;
  int tv = tiles[blockIdx.y];
  int e = tv >> 16, pt = tv & 0xffff;
  int seg0 = offsets[e], cnt = offsets[e + 1] - seg0;
  int n0 = blockIdx.x * BN;

  __shared__ bf16 As[2 * HTILE];   // halves at 0, HTILE
  __shared__ bf16 Bg[2 * HTILE];
  __shared__ bf16 Bu[2 * HTILE];

  int tid = threadIdx.x, lane = tid & 63, wid = tid >> 6;
  int wm = wid >> 1, wn = wid & 1, l15 = lane & 15, l16 = lane >> 4;

  int srow1 = tid >> 2, srow2 = 64 + srow1;
  int kc = (tid & 3) * 8;
  int p1 = pt * BM + srow1, p2 = pt * BM + srow2;
  const bf16* a1 = xb + (size_t)(perm[seg0 + (p1 < cnt ? p1 : 0)] >> 1) * H_DIM + kc;
  const bf16* a2 = xb + (size_t)(perm[seg0 + (p2 < cnt ? p2 : 0)] >> 1) * H_DIM + kc;
  const bf16* g1 = WgT + ((size_t)e * I_DIM + n0 + srow1) * H_DIM + kc;
  const bf16* g2 = WgT + ((size_t)e * I_DIM + n0 + srow2) * H_DIM + kc;
  const bf16* u1 = WuT + ((size_t)e * I_DIM + n0 + srow1) * H_DIM + kc;
  const bf16* u2 = WuT + ((size_t)e * I_DIM + n0 + srow2) * H_DIM + kc;
  bf16* lA1 = &As[tid * 8];       bf16* lA2 = &As[2048 + tid * 8];
  bf16* lG1 = &Bg[tid * 8];       bf16* lG2 = &Bg[2048 + tid * 8];
  bf16* lU1 = &Bu[tid * 8];       bf16* lU2 = &Bu[2048 + tid * 8];

  f32x4 accg[4][4], accu[4][4];
#pragma unroll
  for (int m = 0; m < 4; ++m)
#pragma unroll
    for (int n = 0; n < 4; ++n) {
      accg[m][n] = (f32x4){0.f, 0.f, 0.f, 0.f};
      accu[m][n] = (f32x4){0.f, 0.f, 0.f, 0.f};
    }

  for (int k0 = 0; k0 < H_DIM; k0 += 2 * BK) {
    GL16(a1 + k0, lA1);            GL16(a2 + k0, lA2);
    GL16(a1 + k0 + BK, lA1 + HTILE); GL16(a2 + k0 + BK, lA2 + HTILE);
    GL16(g1 + k0, lG1);            GL16(g2 + k0, lG2);
    GL16(g1 + k0 + BK, lG1 + HTILE); GL16(g2 + k0 + BK, lG2 + HTILE);
    GL16(u1 + k0, lU1);            GL16(u2 + k0, lU2);
    GL16(u1 + k0 + BK, lU1 + HTILE); GL16(u2 + k0 + BK, lU2 + HTILE);
    __syncthreads();               // drains vmcnt -> both halves ready

#pragma unroll
    for (int kk = 0; kk < 2; ++kk) {
      const bf16* Ab = &As[kk * HTILE];
      const bf16* Gb = &Bg[kk * HTILE];
      const bf16* Ub = &Bu[kk * HTILE];
      bf16x8 af[4], bg[4], bu[4];
#pragma unroll
      for (int m = 0; m < 4; ++m)
        af[m] = *reinterpret_cast<const bf16x8*>(&Ab[(wm * 64 + m * 16 + l15) * BK + l16 * 8]);
#pragma unroll
      for (int n = 0; n < 4; ++n) {
        bg[n] = *reinterpret_cast<const bf16x8*>(&Gb[(wn * 64 + n * 16 + l15) * BK + l16 * 8]);
        bu[n] = *reinterpret_cast<const bf16x8*>(&Ub[(wn * 64 + n * 16 + l15) * BK + l16 * 8]);
      }
#pragma unroll
      for (int m = 0; m < 4; ++m)
#pragma unroll
        for (int n = 0; n < 4; ++n) {
          accg[m][n] = __builtin_amdgcn_mfma_f32_16x16x32_bf16(af[m], bg[n], accg[m][n], 0, 0, 0);
          accu[m][n] = __builtin_amdgcn_mfma_f32_16x16x32_bf16(af[m], bu[n], accu[m][n], 0, 0, 0);
        }
    }
    __syncthreads();
  }

#pragma unroll
  for (int m = 0; m < 4; ++m) {
#pragma unroll
    for (int r = 0; r < 4; ++r) {
      int p_glob = pt * BM + wm * 64 + m * 16 + l16 * 4 + r;
      if (p_glob < cnt) {
        bf16* hrow = hidden + (size_t)(seg0 + p_glob) * I_DIM;
#pragma unroll
        for (int n = 0; n < 4; ++n) {
          int col = n0 + wn * 64 + n * 16 + l15;
          float g = accg[m][n][r];
          float u = accu[m][n][r];
          float h = g / (1.f + __expf(-g)) * u;
          hrow[col] = (bf16)h;
        }
      }
    }
  }
}

// ------- down grouped GEMM: split-K x2 bf16 partials, K=64/barrier (R13 proven) -------
__global__ __launch_bounds__(256, 2) void k_down(const bf16* __restrict__ hidden,
                                                 const bf16* __restrict__ WdT,
                                                 const int* __restrict__ perm,
                                                 const int* __restrict__ offsets,
                                                 const int* __restrict__ tiles,
                                                 const int* __restrict__ n_tiles,
                                                 bf16* __restrict__ pair_half) {
  if ((int)blockIdx.y >= *n_tiles) return;
  int tv = tiles[blockIdx.y];
  int e = tv >> 16, pt = tv & 0xffff;
  int seg0 = offsets[e], cnt = offsets[e + 1] - seg0;
  int n0 = blockIdx.x * BN;
  int kz = blockIdx.z * (I_DIM / 2);
  bf16* pout = pair_half + (size_t)blockIdx.z * 2 * T_TOK * H_DIM;

  __shared__ bf16 As[2 * HTILE];
  __shared__ bf16 Bs[2 * HTILE];

  int tid = threadIdx.x, lane = tid & 63, wid = tid >> 6;
  int wm = wid >> 1, wn = wid & 1, l15 = lane & 15, l16 = lane >> 4;

  int srow1 = tid >> 2, srow2 = 64 + srow1;
  int kc = (tid & 3) * 8;
  int p1 = pt * BM + srow1, p2 = pt * BM + srow2;
  const bf16* a1 = hidden + (size_t)(seg0 + (p1 < cnt ? p1 : 0)) * I_DIM + kz + kc;
  const bf16* a2 = hidden + (size_t)(seg0 + (p2 < cnt ? p2 : 0)) * I_DIM + kz + kc;
  const bf16* b1 = WdT + ((size_t)e * H_DIM + n0 + srow1) * I_DIM + kz + kc;
  const bf16* b2 = WdT + ((size_t)e * H_DIM + n0 + srow2) * I_DIM + kz + kc;
  bf16* lA1 = &As[tid * 8];  bf16* lA2 = &As[2048 + tid * 8];
  bf16* lB1 = &Bs[tid * 8];  bf16* lB2 = &Bs[2048 + tid * 8];

  f32x4 acc[4][4];
#pragma unroll
  for (int m = 0; m < 4; ++m)
#pragma unroll
    for (int n = 0; n < 4; ++n) acc[m][n] = (f32x4){0.f, 0.f, 0.f, 0.f};

  for (int k0 = 0; k0 < I_DIM / 2; k0 += 2 * BK) {
    GL16(a1 + k0, lA1);            GL16(a2 + k0, lA2);
    GL16(a1 + k0 + BK, lA1 + HTILE); GL16(a2 + k0 + BK, lA2 + HTILE);
    GL16(b1 + k0, lB1);            GL16(b2 + k0, lB2);
    GL16(b1 + k0 + BK, lB1 + HTILE); GL16(b2 + k0 + BK, lB2 + HTILE);
    __syncthreads();

#pragma unroll
    for (int kk = 0; kk < 2; ++kk) {
      const bf16* Ab = &As[kk * HTILE];
      const bf16* Bb = &Bs[kk * HTILE];
      bf16x8 af[4], bfr[4];
#pragma unroll
      for (int m = 0; m < 4; ++m)
        af[m] = *reinterpret_cast<const bf16x8*>(&Ab[(wm * 64 + m * 16 + l15) * BK + l16 * 8]);
#pragma unroll
      for (int n = 0; n < 4; ++n)
        bfr[n] = *reinterpret_cast<const bf16x8*>(&Bb[(wn * 64 + n * 16 + l15) * BK + l16 * 8]);
#pragma unroll
      for (int m = 0; m < 4; ++m)
#pragma unroll
        for (int n = 0; n < 4; ++n)
          acc[m][n] = __builtin_amdgcn_mfma_f32_16x16x32_bf16(af[m], bfr[n], acc[m][n], 0, 0, 0);
    }
    __syncthreads();
  }

#pragma unroll
  for (int m = 0; m < 4; ++m) {
#pragma unroll
    for (int r = 0; r < 4; ++r) {
      int p_glob = pt * BM + wm * 64 + m * 16 + l16 * 4 + r;
      if (p_glob < cnt) {
        int pair = perm[seg0 + p_glob];
        bf16* orow = pout + (size_t)pair * H_DIM;
#pragma unroll
        for (int n = 0; n < 4; ++n) {
          int col = n0 + wn * 64 + n * 16 + l15;
          orow[col] = (bf16)acc[m][n][r];
        }
      }
    }
  }
}

// ------- combine: out[t] = w0*(z0[2t]+z1[2t]) + w1*(z0[2t+1]+z1[2t+1]) -------
__global__ __launch_bounds__(256) void k_combine(const bf16* __restrict__ pair_half,
                                                 const float* __restrict__ rw,
                                                 float* __restrict__ out) {
  int t = blockIdx.x;
  int c = threadIdx.x;
  const bf16* z0 = pair_half;
  const bf16* z1 = pair_half + (size_t)2 * T_TOK * H_DIM;
  float w0 = rw[2 * t];
  float w1 = rw[2 * t + 1];
  size_t r0 = (size_t)(2 * t) * H_DIM + c * 4;
  size_t r1 = (size_t)(2 * t + 1) * H_DIM + c * 4;
  bf16x4 a0 = *reinterpret_cast<const bf16x4*>(z0 + r0);
  bf16x4 a1 = *reinterpret_cast<const bf16x4*>(z1 + r0);
  bf16x4 b0 = *reinterpret_cast<const bf16x4*>(z0 + r1);
  bf16x4 b1 = *reinterpret_cast<const bf16x4*>(z1 + r1);
  float4 o;
  o.x = w0 * ((float)a0[0] + (float)a1[0]) + w1 * ((float)b0[0] + (float)b1[0]);
  o.y = w0 * ((float)a0[1] + (float)a1[1]) + w1 * ((float)b0[1] + (float)b1[1]);
  o.z = w0 * ((float)a0[2] + (float)a1[2]) + w1 * ((float)b0[2] + (float)b1[2]);
  o.w = w0 * ((float)a0[3] + (float)a1[3]) + w1 * ((float)b0[3] + (float)b1[3]);
  *reinterpret_cast<float4*>(out + (size_t)t * H_DIM + c * 4) = o;
}

extern "C" void kernel_launch(void* const* d_in, const int* in_sizes, int n_in,
                              void* d_out, int out_size, void* d_ws, size_t ws_size,
                              hipStream_t stream) {
  const float* x  = (const float*)d_in[0];
  const float* Wr = (const float*)d_in[1];
  const float* Wg = (const float*)d_in[2];
  const float* Wu = (const float*)d_in[3];
  const float* Wd = (const float*)d_in[4];
  float* out = (float*)d_out;

  char* ws = (char*)d_ws;
  int*   counts  = (int*)(ws);
  int*   cursor  = (int*)(ws + 256);
  int*   offsets = (int*)(ws + 512);
  int*   n_tiles = (int*)(ws + 768);
  int*   tiles   = (int*)(ws + 1024);
  int*   ridx    = (int*)(ws + 64 * 1024);
  float* rw      = (float*)(ws + 128 * 1024);
  int*   perm    = (int*)(ws + 192 * 1024);
  bf16*  xb      = (bf16*)(ws + (1ull << 20));
  bf16*  WgT     = (bf16*)(ws + (16ull << 20));
  bf16*  WuT     = (bf16*)(ws + (66ull << 20));
  bf16*  WdT     = (bf16*)(ws + (116ull << 20));
  bf16*  hidden  = (bf16*)(ws + (166ull << 20));
  bf16*  pair_half = (bf16*)(ws + (212ull << 20));   // [2][8192][1024] bf16 = 32 MiB

  hipMemsetAsync(counts, 0, 64, stream);
  k_prepass<<<dim3(PRE_BLKS), dim3(256), 0, stream>>>(
      x, xb, Wg, Wu, Wd, WgT, WuT, WdT, Wr, ridx, rw, counts);
  k_scan<<<dim3(1), dim3(64), 0, stream>>>(counts, offsets, cursor, tiles, n_tiles);
  k_scatter<<<dim3((T_TOK + 255) / 256), dim3(256), 0, stream>>>(ridx, offsets, cursor, perm);
  k_gateup<<<dim3(I_DIM / BN, MAXTILE), dim3(256), 0, stream>>>(
      xb, WgT, WuT, perm, offsets, tiles, n_tiles, hidden);
  k_down<<<dim3(H_DIM / BN, MAXTILE, 2), dim3(256), 0, stream>>>(
      hidden, WdT, perm, offsets, tiles, n_tiles, pair_half);
  k_combine<<<dim3(T_TOK), dim3(256), 0, stream>>>(pair_half, rw, out);
}

// Round 18
// 441.359 us; speedup vs baseline: 1.4755x; 1.0298x over previous
//
#include <hip/hip_runtime.h>
#include <cstdint>
#include <cstddef>

#define T_TOK 4096
#define H_DIM 1024
#define I_DIM 2816
#define E_NUM 9
#define MAXTILE 76

typedef __bf16 bf16;
typedef bf16 bf16x4 __attribute__((ext_vector_type(4)));
typedef bf16 bf16x8 __attribute__((ext_vector_type(8)));
typedef float f32x4 __attribute__((ext_vector_type(4)));

constexpr int BM = 128, BN = 128, BK = 32;
constexpr int HTILE = BM * BK;          // 4096 elems = 8KB per half
constexpr size_t HI = (size_t)H_DIM * I_DIM;

// pre1 mega-kernel block ranges: xcast | Wg/Wu transpose | router
constexpr int XCAST_BLKS  = T_TOK * H_DIM / 2048;                    // 2048
constexpr int TGU_BLKS    = (I_DIM / 64) * (H_DIM / 64) * 2 * E_NUM; // 12672
constexpr int ROUTER_BLKS = T_TOK / 4;                               // 1024
constexpr int PRE1_BLKS   = XCAST_BLKS + TGU_BLKS + ROUTER_BLKS;

// main1 mega-kernel: gateup tiles first, Wd-transpose blocks trail into the gaps
constexpr int GU_BLKS = (I_DIM / BN) * MAXTILE;                      // 1672
constexpr int TD_BLKS = (H_DIM / 64) * (I_DIM / 64) * E_NUM;         // 6336
constexpr int MAIN1_BLKS = GU_BLKS + TD_BLKS;

// async global->LDS, 16B per lane; LDS dest must be linear (wave-uniform base + lane*16)
#define GL16(gp, lp)                                                                   \
  __builtin_amdgcn_global_load_lds((const __attribute__((address_space(1))) void*)(gp), \
                                   (__attribute__((address_space(3))) void*)(lp), 16, 0, 0)

// ------- transpose+convert core: GL16-staged fp32 tile (16KB), bf16x8 writes -------
__device__ __forceinline__ void transpose_tile(float* __restrict__ tile,
                                               const float* __restrict__ src,
                                               bf16* __restrict__ dst, int R, int C,
                                               int bx, int by) {
  int r0 = by * 64, c0 = bx * 64;
  int t = threadIdx.x;
#pragma unroll
  for (int h = 0; h < 4; ++h) {
    int idx = h * 256 + t;                 // 16B chunk id; 16 chunks per 64-float row
    int row = idx >> 4;
    int col = (idx & 15) * 4;
    GL16(src + (size_t)(r0 + row) * C + c0 + col, &tile[idx * 4]);
  }
  __syncthreads();                         // drains vmcnt -> tile resident
  int oc = t >> 2;                         // [0,64) output column
  int q  = t & 3;                          // row quarter
  bf16x8 w0, w1;
#pragma unroll
  for (int j = 0; j < 8; ++j) w0[j] = (bf16)tile[(q * 16 + j) * 64 + oc];
#pragma unroll
  for (int j = 0; j < 8; ++j) w1[j] = (bf16)tile[(q * 16 + 8 + j) * 64 + oc];
  bf16* dp = dst + (size_t)(c0 + oc) * R + r0 + q * 16;
  *reinterpret_cast<bf16x8*>(dp)     = w0;
  *reinterpret_cast<bf16x8*>(dp + 8) = w1;
}

// ------- pre1: xcast | transpose Wg/Wu | router (everything gateup needs) -------
__global__ __launch_bounds__(256) void k_pre1(const float* __restrict__ x,
                                              bf16* __restrict__ xb,
                                              const float* __restrict__ Wg,
                                              const float* __restrict__ Wu,
                                              bf16* __restrict__ WgT,
                                              bf16* __restrict__ WuT,
                                              const float* __restrict__ Wr,
                                              int* __restrict__ ridx,
                                              float* __restrict__ rw,
                                              int* __restrict__ counts) {
  __shared__ float tile[64 * 64];
  int b = blockIdx.x;

  if (b < XCAST_BLKS) {                       // ---- x: fp32 -> bf16 ----
    size_t i = ((size_t)b * 256 + threadIdx.x) * 8;
    float4 a = *reinterpret_cast<const float4*>(x + i);
    float4 c = *reinterpret_cast<const float4*>(x + i + 4);
    bf16x8 v;
    v[0]=(bf16)a.x; v[1]=(bf16)a.y; v[2]=(bf16)a.z; v[3]=(bf16)a.w;
    v[4]=(bf16)c.x; v[5]=(bf16)c.y; v[6]=(bf16)c.z; v[7]=(bf16)c.w;
    *reinterpret_cast<bf16x8*>(xb + i) = v;
    return;
  }
  b -= XCAST_BLKS;

  if (b < TGU_BLKS) {                         // ---- Wg/Wu transpose [H][I]->[I][H] ----
    int bx = b % (I_DIM / 64);
    int rest = b / (I_DIM / 64);
    int by = rest % (H_DIM / 64);
    int z  = rest / (H_DIM / 64);             // [0,18)
    const float* src = (z < 9) ? (Wg + (size_t)z * HI) : (Wu + (size_t)(z - 9) * HI);
    bf16* dst = (z < 9) ? (WgT + (size_t)z * HI) : (WuT + (size_t)(z - 9) * HI);
    transpose_tile(tile, src, dst, H_DIM, I_DIM, bx, by);
    return;
  }
  b -= TGU_BLKS;

  // ---- router: fp32 logits, softmax top-2, renormalized (identical math) ----
  {
    int lane = threadIdx.x & 63;
    int wid  = threadIdx.x >> 6;
    int t = b * 4 + wid;
    const float* xr = x + (size_t)t * H_DIM;
    float acc[E_NUM];
#pragma unroll
    for (int e = 0; e < E_NUM; ++e) acc[e] = 0.f;
    for (int h = lane; h < H_DIM; h += 64) {
      float xv = xr[h];
      const float* wr = Wr + h * E_NUM;
#pragma unroll
      for (int e = 0; e < E_NUM; ++e) acc[e] += xv * wr[e];
    }
#pragma unroll
    for (int off = 32; off > 0; off >>= 1) {
#pragma unroll
      for (int e = 0; e < E_NUM; ++e) acc[e] += __shfl_xor(acc[e], off);
    }
    if (lane == 0) {
      int i0 = 0;
#pragma unroll
      for (int e = 1; e < E_NUM; ++e) if (acc[e] > acc[i0]) i0 = e;
      int i1 = (i0 == 0) ? 1 : 0;
#pragma unroll
      for (int e = 0; e < E_NUM; ++e) if (e != i0 && acc[e] > acc[i1]) i1 = e;
      float r  = expf(acc[i1] - acc[i0]);
      float w0 = 1.f / (1.f + r);
      float w1 = r / (1.f + r);
      ridx[2 * t]     = i0;
      ridx[2 * t + 1] = i1;
      rw[2 * t]     = w0;
      rw[2 * t + 1] = w1;
      atomicAdd(&counts[i0], 1);
      atomicAdd(&counts[i1], 1);
    }
  }
}

// ------- scan: counts -> offsets, compact tile list, zero cursors -------
__global__ void k_scan(const int* __restrict__ counts, int* __restrict__ offsets,
                       int* __restrict__ cursor, int* __restrict__ tiles,
                       int* __restrict__ n_tiles) {
  if (threadIdx.x == 0) {
    int s = 0, nt = 0;
    for (int e = 0; e < E_NUM; ++e) {
      offsets[e] = s;
      int c = counts[e];
      for (int pt = 0; pt * BM < c && nt < MAXTILE; ++pt) tiles[nt++] = (e << 16) | pt;
      s += c;
    }
    offsets[E_NUM] = s;
    *n_tiles = nt;
  }
  if (threadIdx.x < E_NUM) cursor[threadIdx.x] = 0;
}

// ---------------- scatter pair ids into expert-sorted perm ----------------
__global__ __launch_bounds__(256) void k_scatter(const int* __restrict__ ridx,
                                                 const int* __restrict__ offsets,
                                                 int* __restrict__ cursor,
                                                 int* __restrict__ perm) {
  int t = blockIdx.x * 256 + threadIdx.x;
  if (t >= T_TOK) return;
#pragma unroll
  for (int k = 0; k < 2; ++k) {
    int e = ridx[2 * t + k];
    int pos = atomicAdd(&cursor[e], 1);
    perm[offsets[e] + pos] = 2 * t + k;
  }
}

// ------- main1: gateup GEMM blocks first; Wd-transpose blocks trail into CU gaps -------
// Shared 48KB LDS arena aliased by both branches. gateup branch identical to the
// proven (256,2) BK=64 kernel (146us); TD blocks are memory-bound and fill the
// MFMA-heavy gateup generations' idle slots + tail.
__global__ __launch_bounds__(256, 2) void k_main1(const bf16* __restrict__ xb,
                                                  const bf16* __restrict__ WgT,
                                                  const bf16* __restrict__ WuT,
                                                  const int* __restrict__ perm,
                                                  const int* __restrict__ offsets,
                                                  const int* __restrict__ tiles,
                                                  const int* __restrict__ n_tiles,
                                                  bf16* __restrict__ hidden,
                                                  const float* __restrict__ Wd,
                                                  bf16* __restrict__ WdT) {
  __shared__ char smem[6 * HTILE * 2];   // 48KB arena
  int b = blockIdx.x;

  if (b >= GU_BLKS) {                    // ---- trailing Wd transpose [I][H]->[H][I] ----
    b -= GU_BLKS;
    int bx = b % (H_DIM / 64);
    int rest = b / (H_DIM / 64);
    int by = rest % (I_DIM / 64);
    int z  = rest / (I_DIM / 64);        // [0,9)
    transpose_tile((float*)smem, Wd + (size_t)z * HI, WdT + (size_t)z * HI,
                   I_DIM, H_DIM, bx, by);
    return;
  }

  // ---- gateup: b = tile-major flatten of (y=tile, x=panel) ----
  int ty = b / (I_DIM / BN);
  int n0 = (b % (I_DIM / BN)) * BN;
  if (ty >= *n_tiles) return;
  int tv = tiles[ty];
  int e = tv >> 16, pt = tv & 0xffff;
  int seg0 = offsets[e], cnt = offsets[e + 1] - seg0;

  bf16* As = (bf16*)smem;                // [2*HTILE]
  bf16* Bg = As + 2 * HTILE;
  bf16* Bu = As + 4 * HTILE;

  int tid = threadIdx.x, lane = tid & 63, wid = tid >> 6;
  int wm = wid >> 1, wn = wid & 1, l15 = lane & 15, l16 = lane >> 4;

  int srow1 = tid >> 2, srow2 = 64 + srow1;
  int kc = (tid & 3) * 8;
  int p1 = pt * BM + srow1, p2 = pt * BM + srow2;
  const bf16* a1 = xb + (size_t)(perm[seg0 + (p1 < cnt ? p1 : 0)] >> 1) * H_DIM + kc;
  const bf16* a2 = xb + (size_t)(perm[seg0 + (p2 < cnt ? p2 : 0)] >> 1) * H_DIM + kc;
  const bf16* g1 = WgT + ((size_t)e * I_DIM + n0 + srow1) * H_DIM + kc;
  const bf16* g2 = WgT + ((size_t)e * I_DIM + n0 + srow2) * H_DIM + kc;
  const bf16* u1 = WuT + ((size_t)e * I_DIM + n0 + srow1) * H_DIM + kc;
  const bf16* u2 = WuT + ((size_t)e * I_DIM + n0 + srow2) * H_DIM + kc;
  bf16* lA1 = &As[tid * 8];       bf16* lA2 = &As[2048 + tid * 8];
  bf16* lG1 = &Bg[tid * 8];       bf16* lG2 = &Bg[2048 + tid * 8];
  bf16* lU1 = &Bu[tid * 8];       bf16* lU2 = &Bu[2048 + tid * 8];

  f32x4 accg[4][4], accu[4][4];
#pragma unroll
  for (int m = 0; m < 4; ++m)
#pragma unroll
    for (int n = 0; n < 4; ++n) {
      accg[m][n] = (f32x4){0.f, 0.f, 0.f, 0.f};
      accu[m][n] = (f32x4){0.f, 0.f, 0.f, 0.f};
    }

  for (int k0 = 0; k0 < H_DIM; k0 += 2 * BK) {
    GL16(a1 + k0, lA1);            GL16(a2 + k0, lA2);
    GL16(a1 + k0 + BK, lA1 + HTILE); GL16(a2 + k0 + BK, lA2 + HTILE);
    GL16(g1 + k0, lG1);            GL16(g2 + k0, lG2);
    GL16(g1 + k0 + BK, lG1 + HTILE); GL16(g2 + k0 + BK, lG2 + HTILE);
    GL16(u1 + k0, lU1);            GL16(u2 + k0, lU2);
    GL16(u1 + k0 + BK, lU1 + HTILE); GL16(u2 + k0 + BK, lU2 + HTILE);
    __syncthreads();               // drains vmcnt -> both halves ready

#pragma unroll
    for (int kk = 0; kk < 2; ++kk) {
      const bf16* Ab = &As[kk * HTILE];
      const bf16* Gb = &Bg[kk * HTILE];
      const bf16* Ub = &Bu[kk * HTILE];
      bf16x8 af[4], bg[4], bu[4];
#pragma unroll
      for (int m = 0; m < 4; ++m)
        af[m] = *reinterpret_cast<const bf16x8*>(&Ab[(wm * 64 + m * 16 + l15) * BK + l16 * 8]);
#pragma unroll
      for (int n = 0; n < 4; ++n) {
        bg[n] = *reinterpret_cast<const bf16x8*>(&Gb[(wn * 64 + n * 16 + l15) * BK + l16 * 8]);
        bu[n] = *reinterpret_cast<const bf16x8*>(&Ub[(wn * 64 + n * 16 + l15) * BK + l16 * 8]);
      }
#pragma unroll
      for (int m = 0; m < 4; ++m)
#pragma unroll
        for (int n = 0; n < 4; ++n) {
          accg[m][n] = __builtin_amdgcn_mfma_f32_16x16x32_bf16(af[m], bg[n], accg[m][n], 0, 0, 0);
          accu[m][n] = __builtin_amdgcn_mfma_f32_16x16x32_bf16(af[m], bu[n], accu[m][n], 0, 0, 0);
        }
    }
    __syncthreads();
  }

#pragma unroll
  for (int m = 0; m < 4; ++m) {
#pragma unroll
    for (int r = 0; r < 4; ++r) {
      int p_glob = pt * BM + wm * 64 + m * 16 + l16 * 4 + r;
      if (p_glob < cnt) {
        bf16* hrow = hidden + (size_t)(seg0 + p_glob) * I_DIM;
#pragma unroll
        for (int n = 0; n < 4; ++n) {
          int col = n0 + wn * 64 + n * 16 + l15;
          float g = accg[m][n][r];
          float u = accu[m][n][r];
          float h = g / (1.f + __expf(-g)) * u;
          hrow[col] = (bf16)h;
        }
      }
    }
  }
}

// ------- down grouped GEMM: split-K x2 bf16 partials, K=64/barrier (R13 proven) -------
__global__ __launch_bounds__(256, 2) void k_down(const bf16* __restrict__ hidden,
                                                 const bf16* __restrict__ WdT,
                                                 const int* __restrict__ perm,
                                                 const int* __restrict__ offsets,
                                                 const int* __restrict__ tiles,
                                                 const int* __restrict__ n_tiles,
                                                 bf16* __restrict__ pair_half) {
  if ((int)blockIdx.y >= *n_tiles) return;
  int tv = tiles[blockIdx.y];
  int e = tv >> 16, pt = tv & 0xffff;
  int seg0 = offsets[e], cnt = offsets[e + 1] - seg0;
  int n0 = blockIdx.x * BN;
  int kz = blockIdx.z * (I_DIM / 2);
  bf16* pout = pair_half + (size_t)blockIdx.z * 2 * T_TOK * H_DIM;

  __shared__ bf16 As[2 * HTILE];
  __shared__ bf16 Bs[2 * HTILE];

  int tid = threadIdx.x, lane = tid & 63, wid = tid >> 6;
  int wm = wid >> 1, wn = wid & 1, l15 = lane & 15, l16 = lane >> 4;

  int srow1 = tid >> 2, srow2 = 64 + srow1;
  int kc = (tid & 3) * 8;
  int p1 = pt * BM + srow1, p2 = pt * BM + srow2;
  const bf16* a1 = hidden + (size_t)(seg0 + (p1 < cnt ? p1 : 0)) * I_DIM + kz + kc;
  const bf16* a2 = hidden + (size_t)(seg0 + (p2 < cnt ? p2 : 0)) * I_DIM + kz + kc;
  const bf16* b1 = WdT + ((size_t)e * H_DIM + n0 + srow1) * I_DIM + kz + kc;
  const bf16* b2 = WdT + ((size_t)e * H_DIM + n0 + srow2) * I_DIM + kz + kc;
  bf16* lA1 = &As[tid * 8];  bf16* lA2 = &As[2048 + tid * 8];
  bf16* lB1 = &Bs[tid * 8];  bf16* lB2 = &Bs[2048 + tid * 8];

  f32x4 acc[4][4];
#pragma unroll
  for (int m = 0; m < 4; ++m)
#pragma unroll
    for (int n = 0; n < 4; ++n) acc[m][n] = (f32x4){0.f, 0.f, 0.f, 0.f};

  for (int k0 = 0; k0 < I_DIM / 2; k0 += 2 * BK) {
    GL16(a1 + k0, lA1);            GL16(a2 + k0, lA2);
    GL16(a1 + k0 + BK, lA1 + HTILE); GL16(a2 + k0 + BK, lA2 + HTILE);
    GL16(b1 + k0, lB1);            GL16(b2 + k0, lB2);
    GL16(b1 + k0 + BK, lB1 + HTILE); GL16(b2 + k0 + BK, lB2 + HTILE);
    __syncthreads();

#pragma unroll
    for (int kk = 0; kk < 2; ++kk) {
      const bf16* Ab = &As[kk * HTILE];
      const bf16* Bb = &Bs[kk * HTILE];
      bf16x8 af[4], bfr[4];
#pragma unroll
      for (int m = 0; m < 4; ++m)
        af[m] = *reinterpret_cast<const bf16x8*>(&Ab[(wm * 64 + m * 16 + l15) * BK + l16 * 8]);
#pragma unroll
      for (int n = 0; n < 4; ++n)
        bfr[n] = *reinterpret_cast<const bf16x8*>(&Bb[(wn * 64 + n * 16 + l15) * BK + l16 * 8]);
#pragma unroll
      for (int m = 0; m < 4; ++m)
#pragma unroll
        for (int n = 0; n < 4; ++n)
          acc[m][n] = __builtin_amdgcn_mfma_f32_16x16x32_bf16(af[m], bfr[n], acc[m][n], 0, 0, 0);
    }
    __syncthreads();
  }

#pragma unroll
  for (int m = 0; m < 4; ++m) {
#pragma unroll
    for (int r = 0; r < 4; ++r) {
      int p_glob = pt * BM + wm * 64 + m * 16 + l16 * 4 + r;
      if (p_glob < cnt) {
        int pair = perm[seg0 + p_glob];
        bf16* orow = pout + (size_t)pair * H_DIM;
#pragma unroll
        for (int n = 0; n < 4; ++n) {
          int col = n0 + wn * 64 + n * 16 + l15;
          orow[col] = (bf16)acc[m][n][r];
        }
      }
    }
  }
}

// ------- combine: out[t] = w0*(z0[2t]+z1[2t]) + w1*(z0[2t+1]+z1[2t+1]) -------
__global__ __launch_bounds__(256) void k_combine(const bf16* __restrict__ pair_half,
                                                 const float* __restrict__ rw,
                                                 float* __restrict__ out) {
  int t = blockIdx.x;
  int c = threadIdx.x;
  const bf16* z0 = pair_half;
  const bf16* z1 = pair_half + (size_t)2 * T_TOK * H_DIM;
  float w0 = rw[2 * t];
  float w1 = rw[2 * t + 1];
  size_t r0 = (size_t)(2 * t) * H_DIM + c * 4;
  size_t r1 = (size_t)(2 * t + 1) * H_DIM + c * 4;
  bf16x4 a0 = *reinterpret_cast<const bf16x4*>(z0 + r0);
  bf16x4 a1 = *reinterpret_cast<const bf16x4*>(z1 + r0);
  bf16x4 b0 = *reinterpret_cast<const bf16x4*>(z0 + r1);
  bf16x4 b1 = *reinterpret_cast<const bf16x4*>(z1 + r1);
  float4 o;
  o.x = w0 * ((float)a0[0] + (float)a1[0]) + w1 * ((float)b0[0] + (float)b1[0]);
  o.y = w0 * ((float)a0[1] + (float)a1[1]) + w1 * ((float)b0[1] + (float)b1[1]);
  o.z = w0 * ((float)a0[2] + (float)a1[2]) + w1 * ((float)b0[2] + (float)b1[2]);
  o.w = w0 * ((float)a0[3] + (float)a1[3]) + w1 * ((float)b0[3] + (float)b1[3]);
  *reinterpret_cast<float4*>(out + (size_t)t * H_DIM + c * 4) = o;
}

extern "C" void kernel_launch(void* const* d_in, const int* in_sizes, int n_in,
                              void* d_out, int out_size, void* d_ws, size_t ws_size,
                              hipStream_t stream) {
  const float* x  = (const float*)d_in[0];
  const float* Wr = (const float*)d_in[1];
  const float* Wg = (const float*)d_in[2];
  const float* Wu = (const float*)d_in[3];
  const float* Wd = (const float*)d_in[4];
  float* out = (float*)d_out;

  char* ws = (char*)d_ws;
  int*   counts  = (int*)(ws);
  int*   cursor  = (int*)(ws + 256);
  int*   offsets = (int*)(ws + 512);
  int*   n_tiles = (int*)(ws + 768);
  int*   tiles   = (int*)(ws + 1024);
  int*   ridx    = (int*)(ws + 64 * 1024);
  float* rw      = (float*)(ws + 128 * 1024);
  int*   perm    = (int*)(ws + 192 * 1024);
  bf16*  xb      = (bf16*)(ws + (1ull << 20));
  bf16*  WgT     = (bf16*)(ws + (16ull << 20));
  bf16*  WuT     = (bf16*)(ws + (66ull << 20));
  bf16*  WdT     = (bf16*)(ws + (116ull << 20));
  bf16*  hidden  = (bf16*)(ws + (166ull << 20));
  bf16*  pair_half = (bf16*)(ws + (212ull << 20));   // [2][8192][1024] bf16 = 32 MiB

  hipMemsetAsync(counts, 0, 64, stream);
  k_pre1<<<dim3(PRE1_BLKS), dim3(256), 0, stream>>>(
      x, xb, Wg, Wu, WgT, WuT, Wr, ridx, rw, counts);
  k_scan<<<dim3(1), dim3(64), 0, stream>>>(counts, offsets, cursor, tiles, n_tiles);
  k_scatter<<<dim3((T_TOK + 255) / 256), dim3(256), 0, stream>>>(ridx, offsets, cursor, perm);
  k_main1<<<dim3(MAIN1_BLKS), dim3(256), 0, stream>>>(
      xb, WgT, WuT, perm, offsets, tiles, n_tiles, hidden, Wd, WdT);
  k_down<<<dim3(H_DIM / BN, MAXTILE, 2), dim3(256), 0, stream>>>(
      hidden, WdT, perm, offsets, tiles, n_tiles, pair_half);
  k_combine<<<dim3(T_TOK), dim3(256), 0, stream>>>(pair_half, rw, out);
}

// Round 19
// 433.504 us; speedup vs baseline: 1.5023x; 1.0181x over previous
//
#include <hip/hip_runtime.h>
#include <cstdint>
#include <cstddef>

#define T_TOK 4096
#define H_DIM 1024
#define I_DIM 2816
#define E_NUM 9
#define MAXTILE 76

typedef __bf16 bf16;
typedef bf16 bf16x4 __attribute__((ext_vector_type(4)));
typedef bf16 bf16x8 __attribute__((ext_vector_type(8)));
typedef float f32x4 __attribute__((ext_vector_type(4)));

constexpr int BM = 128, BN = 128, BK = 32;
constexpr int HTILE = BM * BK;          // 4096 elems = 8KB per half
constexpr size_t HI = (size_t)H_DIM * I_DIM;

// pre1: 1024-thread blocks, 4 sub-jobs each (4x tile-DMAs in flight per CU)
constexpr int TGU_TILES = (I_DIM / 64) * (H_DIM / 64) * 2 * E_NUM;   // 12672
constexpr int TGU4 = TGU_TILES / 4;                                  // 3168
constexpr int XC4  = (T_TOK * H_DIM / 2048) / 4;                     // 512
constexpr int RT4  = T_TOK / 16;                                     // 256
constexpr int PRE1_BLKS = TGU4 + XC4 + RT4;

// main1 mega-kernel: gateup tiles first, Wd-transpose blocks trail into the gaps
constexpr int GU_BLKS = (I_DIM / BN) * MAXTILE;                      // 1672
constexpr int TD_BLKS = (H_DIM / 64) * (I_DIM / 64) * E_NUM;         // 6336
constexpr int MAIN1_BLKS = GU_BLKS + TD_BLKS;

// async global->LDS, 16B per lane; LDS dest must be linear (wave-uniform base + lane*16)
#define GL16(gp, lp)                                                                   \
  __builtin_amdgcn_global_load_lds((const __attribute__((address_space(1))) void*)(gp), \
                                   (__attribute__((address_space(3))) void*)(lp), 16, 0, 0)

// ------- transpose+convert core: GL16-staged fp32 tile (16KB), bf16x8 writes -------
// t in [0,256) is the sub-tile-local thread id.
__device__ __forceinline__ void transpose_tile(float* __restrict__ tile,
                                               const float* __restrict__ src,
                                               bf16* __restrict__ dst, int R, int C,
                                               int bx, int by, int t) {
  int r0 = by * 64, c0 = bx * 64;
#pragma unroll
  for (int h = 0; h < 4; ++h) {
    int idx = h * 256 + t;                 // 16B chunk id; 16 chunks per 64-float row
    int row = idx >> 4;
    int col = (idx & 15) * 4;
    GL16(src + (size_t)(r0 + row) * C + c0 + col, &tile[idx * 4]);
  }
  __syncthreads();                         // drains vmcnt -> all sub-tiles resident
  int oc = t >> 2;                         // [0,64) output column
  int q  = t & 3;                          // row quarter
  bf16x8 w0, w1;
#pragma unroll
  for (int j = 0; j < 8; ++j) w0[j] = (bf16)tile[(q * 16 + j) * 64 + oc];
#pragma unroll
  for (int j = 0; j < 8; ++j) w1[j] = (bf16)tile[(q * 16 + 8 + j) * 64 + oc];
  bf16* dp = dst + (size_t)(c0 + oc) * R + r0 + q * 16;
  *reinterpret_cast<bf16x8*>(dp)     = w0;
  *reinterpret_cast<bf16x8*>(dp + 8) = w1;
}

// ------- pre1 (1024 thr): Wg/Wu transpose x4 | xcast x4 | router x16-token -------
__global__ __launch_bounds__(1024) void k_pre1(const float* __restrict__ x,
                                               bf16* __restrict__ xb,
                                               const float* __restrict__ Wg,
                                               const float* __restrict__ Wu,
                                               bf16* __restrict__ WgT,
                                               bf16* __restrict__ WuT,
                                               const float* __restrict__ Wr,
                                               int* __restrict__ ridx,
                                               float* __restrict__ rw,
                                               int* __restrict__ counts) {
  __shared__ float tiles_lds[4][64 * 64];   // 64KB arena, one 16KB tile per sub-job
  int b = blockIdx.x;
  int sub = threadIdx.x >> 8;               // [0,4)
  int t   = threadIdx.x & 255;

  if (b < TGU4) {                           // ---- Wg/Wu transpose [H][I]->[I][H] ----
    int tile_id = b * 4 + sub;
    int bx = tile_id % (I_DIM / 64);
    int rest = tile_id / (I_DIM / 64);
    int by = rest % (H_DIM / 64);
    int z  = rest / (H_DIM / 64);           // [0,18)
    const float* src = (z < 9) ? (Wg + (size_t)z * HI) : (Wu + (size_t)(z - 9) * HI);
    bf16* dst = (z < 9) ? (WgT + (size_t)z * HI) : (WuT + (size_t)(z - 9) * HI);
    transpose_tile(tiles_lds[sub], src, dst, H_DIM, I_DIM, bx, by, t);
    return;
  }
  b -= TGU4;

  if (b < XC4) {                            // ---- x: fp32 -> bf16 (4 old blocks) ----
    size_t i = (((size_t)b * 4 + sub) * 256 + t) * 8;
    float4 a = *reinterpret_cast<const float4*>(x + i);
    float4 c = *reinterpret_cast<const float4*>(x + i + 4);
    bf16x8 v;
    v[0]=(bf16)a.x; v[1]=(bf16)a.y; v[2]=(bf16)a.z; v[3]=(bf16)a.w;
    v[4]=(bf16)c.x; v[5]=(bf16)c.y; v[6]=(bf16)c.z; v[7]=(bf16)c.w;
    *reinterpret_cast<bf16x8*>(xb + i) = v;
    return;
  }
  b -= XC4;

  // ---- router: 16 tokens per block (one per wave); identical per-token math ----
  {
    int lane = threadIdx.x & 63;
    int wid  = threadIdx.x >> 6;            // [0,16)
    int tok = b * 16 + wid;
    const float* xr = x + (size_t)tok * H_DIM;
    float acc[E_NUM];
#pragma unroll
    for (int e = 0; e < E_NUM; ++e) acc[e] = 0.f;
    for (int h = lane; h < H_DIM; h += 64) {
      float xv = xr[h];
      const float* wr = Wr + h * E_NUM;
#pragma unroll
      for (int e = 0; e < E_NUM; ++e) acc[e] += xv * wr[e];
    }
#pragma unroll
    for (int off = 32; off > 0; off >>= 1) {
#pragma unroll
      for (int e = 0; e < E_NUM; ++e) acc[e] += __shfl_xor(acc[e], off);
    }
    if (lane == 0) {
      int i0 = 0;
#pragma unroll
      for (int e = 1; e < E_NUM; ++e) if (acc[e] > acc[i0]) i0 = e;
      int i1 = (i0 == 0) ? 1 : 0;
#pragma unroll
      for (int e = 0; e < E_NUM; ++e) if (e != i0 && acc[e] > acc[i1]) i1 = e;
      float r  = expf(acc[i1] - acc[i0]);
      float w0 = 1.f / (1.f + r);
      float w1 = r / (1.f + r);
      ridx[2 * tok]     = i0;
      ridx[2 * tok + 1] = i1;
      rw[2 * tok]     = w0;
      rw[2 * tok + 1] = w1;
      atomicAdd(&counts[i0], 1);
      atomicAdd(&counts[i1], 1);
    }
  }
}

// ------- scan: counts -> offsets, compact tile list, zero cursors -------
__global__ void k_scan(const int* __restrict__ counts, int* __restrict__ offsets,
                       int* __restrict__ cursor, int* __restrict__ tiles,
                       int* __restrict__ n_tiles) {
  if (threadIdx.x == 0) {
    int s = 0, nt = 0;
    for (int e = 0; e < E_NUM; ++e) {
      offsets[e] = s;
      int c = counts[e];
      for (int pt = 0; pt * BM < c && nt < MAXTILE; ++pt) tiles[nt++] = (e << 16) | pt;
      s += c;
    }
    offsets[E_NUM] = s;
    *n_tiles = nt;
  }
  if (threadIdx.x < E_NUM) cursor[threadIdx.x] = 0;
}

// ---------------- scatter pair ids into expert-sorted perm ----------------
__global__ __launch_bounds__(256) void k_scatter(const int* __restrict__ ridx,
                                                 const int* __restrict__ offsets,
                                                 int* __restrict__ cursor,
                                                 int* __restrict__ perm) {
  int t = blockIdx.x * 256 + threadIdx.x;
  if (t >= T_TOK) return;
#pragma unroll
  for (int k = 0; k < 2; ++k) {
    int e = ridx[2 * t + k];
    int pos = atomicAdd(&cursor[e], 1);
    perm[offsets[e] + pos] = 2 * t + k;
  }
}

// ------- main1: gateup GEMM blocks first; Wd-transpose blocks trail into CU gaps -------
__global__ __launch_bounds__(256, 2) void k_main1(const bf16* __restrict__ xb,
                                                  const bf16* __restrict__ WgT,
                                                  const bf16* __restrict__ WuT,
                                                  const int* __restrict__ perm,
                                                  const int* __restrict__ offsets,
                                                  const int* __restrict__ tiles,
                                                  const int* __restrict__ n_tiles,
                                                  bf16* __restrict__ hidden,
                                                  const float* __restrict__ Wd,
                                                  bf16* __restrict__ WdT) {
  __shared__ char smem[6 * HTILE * 2];   // 48KB arena
  int b = blockIdx.x;

  if (b >= GU_BLKS) {                    // ---- trailing Wd transpose [I][H]->[H][I] ----
    b -= GU_BLKS;
    int bx = b % (H_DIM / 64);
    int rest = b / (H_DIM / 64);
    int by = rest % (I_DIM / 64);
    int z  = rest / (I_DIM / 64);        // [0,9)
    transpose_tile((float*)smem, Wd + (size_t)z * HI, WdT + (size_t)z * HI,
                   I_DIM, H_DIM, bx, by, threadIdx.x);
    return;
  }

  // ---- gateup: b = tile-major flatten of (y=tile, x=panel) ----
  int ty = b / (I_DIM / BN);
  int n0 = (b % (I_DIM / BN)) * BN;
  if (ty >= *n_tiles) return;
  int tv = tiles[ty];
  int e = tv >> 16, pt = tv & 0xffff;
  int seg0 = offsets[e], cnt = offsets[e + 1] - seg0;

  bf16* As = (bf16*)smem;                // [2*HTILE]
  bf16* Bg = As + 2 * HTILE;
  bf16* Bu = As + 4 * HTILE;

  int tid = threadIdx.x, lane = tid & 63, wid = tid >> 6;
  int wm = wid >> 1, wn = wid & 1, l15 = lane & 15, l16 = lane >> 4;

  int srow1 = tid >> 2, srow2 = 64 + srow1;
  int kc = (tid & 3) * 8;
  int p1 = pt * BM + srow1, p2 = pt * BM + srow2;
  const bf16* a1 = xb + (size_t)(perm[seg0 + (p1 < cnt ? p1 : 0)] >> 1) * H_DIM + kc;
  const bf16* a2 = xb + (size_t)(perm[seg0 + (p2 < cnt ? p2 : 0)] >> 1) * H_DIM + kc;
  const bf16* g1 = WgT + ((size_t)e * I_DIM + n0 + srow1) * H_DIM + kc;
  const bf16* g2 = WgT + ((size_t)e * I_DIM + n0 + srow2) * H_DIM + kc;
  const bf16* u1 = WuT + ((size_t)e * I_DIM + n0 + srow1) * H_DIM + kc;
  const bf16* u2 = WuT + ((size_t)e * I_DIM + n0 + srow2) * H_DIM + kc;
  bf16* lA1 = &As[tid * 8];       bf16* lA2 = &As[2048 + tid * 8];
  bf16* lG1 = &Bg[tid * 8];       bf16* lG2 = &Bg[2048 + tid * 8];
  bf16* lU1 = &Bu[tid * 8];       bf16* lU2 = &Bu[2048 + tid * 8];

  f32x4 accg[4][4], accu[4][4];
#pragma unroll
  for (int m = 0; m < 4; ++m)
#pragma unroll
    for (int n = 0; n < 4; ++n) {
      accg[m][n] = (f32x4){0.f, 0.f, 0.f, 0.f};
      accu[m][n] = (f32x4){0.f, 0.f, 0.f, 0.f};
    }

  for (int k0 = 0; k0 < H_DIM; k0 += 2 * BK) {
    GL16(a1 + k0, lA1);            GL16(a2 + k0, lA2);
    GL16(a1 + k0 + BK, lA1 + HTILE); GL16(a2 + k0 + BK, lA2 + HTILE);
    GL16(g1 + k0, lG1);            GL16(g2 + k0, lG2);
    GL16(g1 + k0 + BK, lG1 + HTILE); GL16(g2 + k0 + BK, lG2 + HTILE);
    GL16(u1 + k0, lU1);            GL16(u2 + k0, lU2);
    GL16(u1 + k0 + BK, lU1 + HTILE); GL16(u2 + k0 + BK, lU2 + HTILE);
    __syncthreads();               // drains vmcnt -> both halves ready

#pragma unroll
    for (int kk = 0; kk < 2; ++kk) {
      const bf16* Ab = &As[kk * HTILE];
      const bf16* Gb = &Bg[kk * HTILE];
      const bf16* Ub = &Bu[kk * HTILE];
      bf16x8 af[4], bg[4], bu[4];
#pragma unroll
      for (int m = 0; m < 4; ++m)
        af[m] = *reinterpret_cast<const bf16x8*>(&Ab[(wm * 64 + m * 16 + l15) * BK + l16 * 8]);
#pragma unroll
      for (int n = 0; n < 4; ++n) {
        bg[n] = *reinterpret_cast<const bf16x8*>(&Gb[(wn * 64 + n * 16 + l15) * BK + l16 * 8]);
        bu[n] = *reinterpret_cast<const bf16x8*>(&Ub[(wn * 64 + n * 16 + l15) * BK + l16 * 8]);
      }
#pragma unroll
      for (int m = 0; m < 4; ++m)
#pragma unroll
        for (int n = 0; n < 4; ++n) {
          accg[m][n] = __builtin_amdgcn_mfma_f32_16x16x32_bf16(af[m], bg[n], accg[m][n], 0, 0, 0);
          accu[m][n] = __builtin_amdgcn_mfma_f32_16x16x32_bf16(af[m], bu[n], accu[m][n], 0, 0, 0);
        }
    }
    __syncthreads();
  }

#pragma unroll
  for (int m = 0; m < 4; ++m) {
#pragma unroll
    for (int r = 0; r < 4; ++r) {
      int p_glob = pt * BM + wm * 64 + m * 16 + l16 * 4 + r;
      if (p_glob < cnt) {
        bf16* hrow = hidden + (size_t)(seg0 + p_glob) * I_DIM;
#pragma unroll
        for (int n = 0; n < 4; ++n) {
          int col = n0 + wn * 64 + n * 16 + l15;
          float g = accg[m][n][r];
          float u = accu[m][n][r];
          float h = g / (1.f + __expf(-g)) * u;
          hrow[col] = (bf16)h;
        }
      }
    }
  }
}

// ------- down grouped GEMM: split-K x2 bf16 partials, K=64/barrier (R13 proven) -------
__global__ __launch_bounds__(256, 2) void k_down(const bf16* __restrict__ hidden,
                                                 const bf16* __restrict__ WdT,
                                                 const int* __restrict__ perm,
                                                 const int* __restrict__ offsets,
                                                 const int* __restrict__ tiles,
                                                 const int* __restrict__ n_tiles,
                                                 bf16* __restrict__ pair_half) {
  if ((int)blockIdx.y >= *n_tiles) return;
  int tv = tiles[blockIdx.y];
  int e = tv >> 16, pt = tv & 0xffff;
  int seg0 = offsets[e], cnt = offsets[e + 1] - seg0;
  int n0 = blockIdx.x * BN;
  int kz = blockIdx.z * (I_DIM / 2);
  bf16* pout = pair_half + (size_t)blockIdx.z * 2 * T_TOK * H_DIM;

  __shared__ bf16 As[2 * HTILE];
  __shared__ bf16 Bs[2 * HTILE];

  int tid = threadIdx.x, lane = tid & 63, wid = tid >> 6;
  int wm = wid >> 1, wn = wid & 1, l15 = lane & 15, l16 = lane >> 4;

  int srow1 = tid >> 2, srow2 = 64 + srow1;
  int kc = (tid & 3) * 8;
  int p1 = pt * BM + srow1, p2 = pt * BM + srow2;
  const bf16* a1 = hidden + (size_t)(seg0 + (p1 < cnt ? p1 : 0)) * I_DIM + kz + kc;
  const bf16* a2 = hidden + (size_t)(seg0 + (p2 < cnt ? p2 : 0)) * I_DIM + kz + kc;
  const bf16* b1 = WdT + ((size_t)e * H_DIM + n0 + srow1) * I_DIM + kz + kc;
  const bf16* b2 = WdT + ((size_t)e * H_DIM + n0 + srow2) * I_DIM + kz + kc;
  bf16* lA1 = &As[tid * 8];  bf16* lA2 = &As[2048 + tid * 8];
  bf16* lB1 = &Bs[tid * 8];  bf16* lB2 = &Bs[2048 + tid * 8];

  f32x4 acc[4][4];
#pragma unroll
  for (int m = 0; m < 4; ++m)
#pragma unroll
    for (int n = 0; n < 4; ++n) acc[m][n] = (f32x4){0.f, 0.f, 0.f, 0.f};

  for (int k0 = 0; k0 < I_DIM / 2; k0 += 2 * BK) {
    GL16(a1 + k0, lA1);            GL16(a2 + k0, lA2);
    GL16(a1 + k0 + BK, lA1 + HTILE); GL16(a2 + k0 + BK, lA2 + HTILE);
    GL16(b1 + k0, lB1);            GL16(b2 + k0, lB2);
    GL16(b1 + k0 + BK, lB1 + HTILE); GL16(b2 + k0 + BK, lB2 + HTILE);
    __syncthreads();

#pragma unroll
    for (int kk = 0; kk < 2; ++kk) {
      const bf16* Ab = &As[kk * HTILE];
      const bf16* Bb = &Bs[kk * HTILE];
      bf16x8 af[4], bfr[4];
#pragma unroll
      for (int m = 0; m < 4; ++m)
        af[m] = *reinterpret_cast<const bf16x8*>(&Ab[(wm * 64 + m * 16 + l15) * BK + l16 * 8]);
#pragma unroll
      for (int n = 0; n < 4; ++n)
        bfr[n] = *reinterpret_cast<const bf16x8*>(&Bb[(wn * 64 + n * 16 + l15) * BK + l16 * 8]);
#pragma unroll
      for (int m = 0; m < 4; ++m)
#pragma unroll
        for (int n = 0; n < 4; ++n)
          acc[m][n] = __builtin_amdgcn_mfma_f32_16x16x32_bf16(af[m], bfr[n], acc[m][n], 0, 0, 0);
    }
    __syncthreads();
  }

#pragma unroll
  for (int m = 0; m < 4; ++m) {
#pragma unroll
    for (int r = 0; r < 4; ++r) {
      int p_glob = pt * BM + wm * 64 + m * 16 + l16 * 4 + r;
      if (p_glob < cnt) {
        int pair = perm[seg0 + p_glob];
        bf16* orow = pout + (size_t)pair * H_DIM;
#pragma unroll
        for (int n = 0; n < 4; ++n) {
          int col = n0 + wn * 64 + n * 16 + l15;
          orow[col] = (bf16)acc[m][n][r];
        }
      }
    }
  }
}

// ------- combine: out[t] = w0*(z0[2t]+z1[2t]) + w1*(z0[2t+1]+z1[2t+1]) -------
__global__ __launch_bounds__(256) void k_combine(const bf16* __restrict__ pair_half,
                                                 const float* __restrict__ rw,
                                                 float* __restrict__ out) {
  int t = blockIdx.x;
  int c = threadIdx.x;
  const bf16* z0 = pair_half;
  const bf16* z1 = pair_half + (size_t)2 * T_TOK * H_DIM;
  float w0 = rw[2 * t];
  float w1 = rw[2 * t + 1];
  size_t r0 = (size_t)(2 * t) * H_DIM + c * 4;
  size_t r1 = (size_t)(2 * t + 1) * H_DIM + c * 4;
  bf16x4 a0 = *reinterpret_cast<const bf16x4*>(z0 + r0);
  bf16x4 a1 = *reinterpret_cast<const bf16x4*>(z1 + r0);
  bf16x4 b0 = *reinterpret_cast<const bf16x4*>(z0 + r1);
  bf16x4 b1 = *reinterpret_cast<const bf16x4*>(z1 + r1);
  float4 o;
  o.x = w0 * ((float)a0[0] + (float)a1[0]) + w1 * ((float)b0[0] + (float)b1[0]);
  o.y = w0 * ((float)a0[1] + (float)a1[1]) + w1 * ((float)b0[1] + (float)b1[1]);
  o.z = w0 * ((float)a0[2] + (float)a1[2]) + w1 * ((float)b0[2] + (float)b1[2]);
  o.w = w0 * ((float)a0[3] + (float)a1[3]) + w1 * ((float)b0[3] + (float)b1[3]);
  *reinterpret_cast<float4*>(out + (size_t)t * H_DIM + c * 4) = o;
}

extern "C" void kernel_launch(void* const* d_in, const int* in_sizes, int n_in,
                              void* d_out, int out_size, void* d_ws, size_t ws_size,
                              hipStream_t stream) {
  const float* x  = (const float*)d_in[0];
  const float* Wr = (const float*)d_in[1];
  const float* Wg = (const float*)d_in[2];
  const float* Wu = (const float*)d_in[3];
  const float* Wd = (const float*)d_in[4];
  float* out = (float*)d_out;

  char* ws = (char*)d_ws;
  int*   counts  = (int*)(ws);
  int*   cursor  = (int*)(ws + 256);
  int*   offsets = (int*)(ws + 512);
  int*   n_tiles = (int*)(ws + 768);
  int*   tiles   = (int*)(ws + 1024);
  int*   ridx    = (int*)(ws + 64 * 1024);
  float* rw      = (float*)(ws + 128 * 1024);
  int*   perm    = (int*)(ws + 192 * 1024);
  bf16*  xb      = (bf16*)(ws + (1ull << 20));
  bf16*  WgT     = (bf16*)(ws + (16ull << 20));
  bf16*  WuT     = (bf16*)(ws + (66ull << 20));
  bf16*  WdT     = (bf16*)(ws + (116ull << 20));
  bf16*  hidden  = (bf16*)(ws + (166ull << 20));
  bf16*  pair_half = (bf16*)(ws + (212ull << 20));   // [2][8192][1024] bf16 = 32 MiB

  hipMemsetAsync(counts, 0, 64, stream);
  k_pre1<<<dim3(PRE1_BLKS), dim3(1024), 0, stream>>>(
      x, xb, Wg, Wu, WgT, WuT, Wr, ridx, rw, counts);
  k_scan<<<dim3(1), dim3(64), 0, stream>>>(counts, offsets, cursor, tiles, n_tiles);
  k_scatter<<<dim3((T_TOK + 255) / 256), dim3(256), 0, stream>>>(ridx, offsets, cursor, perm);
  k_main1<<<dim3(MAIN1_BLKS), dim3(256), 0, stream>>>(
      xb, WgT, WuT, perm, offsets, tiles, n_tiles, hidden, Wd, WdT);
  k_down<<<dim3(H_DIM / BN, MAXTILE, 2), dim3(256), 0, stream>>>(
      hidden, WdT, perm, offsets, tiles, n_tiles, pair_half);
  k_combine<<<dim3(T_TOK), dim3(256), 0, stream>>>(pair_half, rw, out);
}